// Round 17
// baseline (172.357 us; speedup 1.0000x reference)
//
#include <hip/hip_runtime.h>
#include <math.h>

#define DEV __device__ __forceinline__

typedef __attribute__((ext_vector_type(8))) short short8;
typedef __attribute__((ext_vector_type(4))) float f32x4;

DEV float sigmoidf_(float x){ return 1.f/(1.f+__expf(-x)); }
DEV float siluf_(float x){ return x/(1.f+__expf(-x)); }
DEV float softplusf_(float x){ return (x>20.f)? x : log1pf(__expf(x)); }

DEV short bf16rne(float f){
  unsigned u=__float_as_uint(f);
  unsigned r=(u + 0x7FFFu + ((u>>16)&1u))>>16;
  return (short)r;
}
DEV unsigned short bf16u(float f){ return (unsigned short)bf16rne(f); }
DEV float b2f(unsigned short u){ return __uint_as_float(((unsigned)u)<<16); }
DEV float b2fs(short u){ return __uint_as_float(((unsigned)(unsigned short)u)<<16); }

// async global->LDS, 16B per lane
DEV void gll16(const void* g, void* l){
  __builtin_amdgcn_global_load_lds(
      (const __attribute__((address_space(1))) void*)g,
      (__attribute__((address_space(3))) void*)(unsigned)(uintptr_t)l,
      16, 0, 0);
}

// row remap: 0 identity; 1 mamba interleave; 2 shifted-window gather
DEV int map_row(int r, int mode){
  if(mode==1){
    int b=r/4608; int gl=r-b*4608;
    return ((gl&1)*2+b)*2304 + (gl>>1);
  }
  if(mode==2){
    int widx=r>>6, n=r&63;
    int b=widx/36, t=widx-b*36;
    int wi=t/6, wj=t-wi*6;
    int h2=wi*8+(n>>3), w2=wj*8+(n&7);
    int ho=h2+4; if(ho>=48) ho-=48;
    int wo=w2+4; if(wo>=48) wo-=48;
    return b*2304 + ho*48 + wo;
  }
  return r;
}

// ================= unified double-buffered bf16 MFMA GEMM body (dynamic LDS) =================
template<int K>
DEV void gemm_body(const short* __restrict__ A, const short* __restrict__ W,
    const float* __restrict__ bias, const float* __restrict__ res,
    float* __restrict__ Of, short* __restrict__ Ob,
    int N, int ldo, int col_off, int gmode, int smode, int epi,
    int bx, int by, float* __restrict__ pool, short* sMem){
  constexpr int NP=K/64;
  short (*sA)[64][64]=(short(*)[64][64])sMem;
  short (*sB)[64][64]=(short(*)[64][64])(sMem+8192);
  float* sO=(float*)sMem;
  int tid=threadIdx.x, lane=tid&63, wid=tid>>6;
  int m16=lane&15, kq=lane>>4;
  int bm=bx*64, bn=by*64;
  int lrow=lane>>3;
  int lcol=((lane&7)^lrow)<<3;
  int sx=(m16&7)<<3;
  const short* ap[2]; const short* wp[2];
  #pragma unroll
  for(int t=0;t<2;t++){
    int i8=wid+t*4;
    int arow=map_row(bm+i8*8+lrow,gmode);
    ap[t]=A+(size_t)arow*K+lcol;
    int n=bn+i8*8+lrow;
    if(n>=N) n=N-1;                                // clamp: finite garbage, masked at store
    wp[t]=W+(size_t)n*K+lcol;
  }
  f32x4 acc[4];
  #pragma unroll
  for(int ni=0;ni<4;ni++) acc[ni]=(f32x4){0.f,0.f,0.f,0.f};

  auto stage=[&](int p,int b){
    #pragma unroll
    for(int t=0;t<2;t++){
      int i8=wid+t*4;
      gll16(ap[t]+p*64, &sA[b][i8*8][0]);
      gll16(wp[t]+p*64, &sB[b][i8*8][0]);
    }
  };
  auto compute=[&](int p,int b){
    __builtin_amdgcn_s_setprio(1);
    #pragma unroll
    for(int half=0;half<2;half++){
      int k2=(half*32 + kq*8) ^ sx;
      short8 af=*(const short8*)&sA[b][wid*16+m16][k2];
      #pragma unroll
      for(int ni=0;ni<4;ni++){
        short8 bf=*(const short8*)&sB[b][ni*16+m16][k2];
        acc[ni]=__builtin_amdgcn_mfma_f32_16x16x32_bf16(af,bf,acc[ni],0,0,0);
      }
    }
    __builtin_amdgcn_s_setprio(0);
  };

  stage(0,0);
  if(NP>1) stage(1,1);
  #pragma unroll
  for(int p=0;p<NP;p++){
    if(p+1<NP) asm volatile("s_waitcnt vmcnt(4)":::"memory");
    else       asm volatile("s_waitcnt vmcnt(0)":::"memory");
    __builtin_amdgcn_s_barrier();
    compute(p,p&1);
    if(p+2<NP){
      __builtin_amdgcn_s_barrier();
      stage(p+2,p&1);
    }
  }

  __syncthreads();
  {
    int mbase=wid*16+4*kq;
    #pragma unroll
    for(int ni=0;ni<4;ni++)
      #pragma unroll
      for(int r=0;r<4;r++)
        sO[(mbase+r)*65 + ni*16+m16]=acc[ni][r];
  }
  __syncthreads();
  int erow=tid>>3, c0=(tid&7)*8;
  #pragma unroll
  for(int rd=0;rd<2;rd++){
    int ml=rd*32+erow;
    int m=bm+ml;
    int orow=map_row(m,smode);
    float v[8];
    #pragma unroll
    for(int j=0;j<8;j++) v[j]=sO[ml*65+c0+j];
    const float* rp=res? res+(size_t)orow*ldo+col_off : nullptr;
    #pragma unroll
    for(int j=0;j<8;j++){
      int nn=bn+c0+j;
      float val=v[j];
      if(bias && nn<N) val+=bias[nn];
      if(epi==2) val=0.5f*val*(1.f+erff(val*0.70710678118654752f));
      else if(epi==3) val+=rp[nn];
      v[j]=val;
    }
    size_t obase=(size_t)orow*ldo+col_off+bn+c0;
    if(bn+c0+7<N){
      if(Ob){
        short8 w;
        #pragma unroll
        for(int j=0;j<8;j++) w[j]=bf16rne(v[j]);
        *(short8*)(Ob+obase)=w;
      } else {
        float4 f0={v[0],v[1],v[2],v[3]}, f1={v[4],v[5],v[6],v[7]};
        *(float4*)(Of+obase)=f0;
        *(float4*)(Of+obase+4)=f1;
      }
    } else {
      #pragma unroll
      for(int j=0;j<8;j++){
        int nn=bn+c0+j;
        if(nn<N){ if(Ob) Ob[obase+j]=bf16rne(v[j]); else Of[obase+j]=v[j]; }
      }
    }
  }
  if(pool){
    if(tid<64){
      float s=0;
      #pragma unroll 8
      for(int ml=0;ml<64;ml++) s+=sO[ml*65+tid];
      if(bias) s+=64.f*bias[bn+tid];
      atomicAdd(&pool[(bm/2304)*192 + bn+tid], s);
    }
  }
}

template<int K>
__global__ __launch_bounds__(256,4) void k_gemm(const short* __restrict__ A, const short* __restrict__ W,
    const float* __restrict__ bias, const float* __restrict__ res,
    float* __restrict__ Of, short* __restrict__ Ob,
    int N, int ldo, int col_off, int gmode, int smode, int epi, float* __restrict__ pool){
  extern __shared__ short smem[];
  gemm_body<K>(A,W,bias,res,Of,Ob,N,ldo,col_off,gmode,smode,epi,blockIdx.x,blockIdx.y,pool,smem);
}

// merged in_proj + qkv
__global__ __launch_bounds__(256,4) void k_gemm_inqkv(const short* __restrict__ xn,
    const short* __restrict__ w_in, short* __restrict__ zx,
    const short* __restrict__ w_qkv, const float* __restrict__ qkvb, short* __restrict__ qkv){
  extern __shared__ short smem[];
  int by=blockIdx.y;
  const short* W; short* O; const float* bias; int N,ldo,gm,byy;
  if(by<15){ W=w_in;  O=zx;  bias=nullptr; N=902; ldo=904; gm=1; byy=by; }
  else     { W=w_qkv; O=qkv; bias=qkvb;    N=576; ldo=576; gm=2; byy=by-15; }
  gemm_body<192>(xn,W,bias,nullptr,nullptr,O, N,ldo,0, gm,0,0, blockIdx.x,byy, nullptr, smem);
}

// merged mamba out_proj (K=384) + attn proj (K=192) -> xcat disjoint columns
__global__ __launch_bounds__(256,4) void k_gemm_opproj(const short* __restrict__ yn,
    const short* __restrict__ w_out, const short* __restrict__ obuf,
    const short* __restrict__ w_proj, const float* __restrict__ projb, short* __restrict__ xcat){
  extern __shared__ short smem[];
  if(blockIdx.y<3)
    gemm_body<384>(yn,w_out,nullptr,nullptr,nullptr,xcat, 192,384,0, 0,1,0, blockIdx.x,blockIdx.y, nullptr, smem);
  else
    gemm_body<192>(obuf,w_proj,projb,nullptr,nullptr,xcat, 192,384,192, 0,2,0, blockIdx.x,blockIdx.y-3, nullptr, smem);
}

// ---------------- merged LayerNorm1 + weight bf16 pre-convert ----------------
__global__ __launch_bounds__(256) void k_lnw2b(const float* __restrict__ in, const float* __restrict__ w,
    const float* __restrict__ b, short* __restrict__ out,
    const float* __restrict__ w0,const float* __restrict__ w1,const float* __restrict__ w2,
    const float* __restrict__ w3,const float* __restrict__ w4,const float* __restrict__ w5,
    const float* __restrict__ w6, short* __restrict__ dst){
  int bid=blockIdx.x;
  if(bid<2304){
    int warp=threadIdx.x>>6, lane=threadIdx.x&63;
    int row=bid*4+warp;
    const float* ip=in+(size_t)row*192;
    float v0=ip[lane], v1=ip[lane+64], v2=ip[lane+128];
    float s=v0+v1+v2, sq=v0*v0+v1*v1+v2*v2;
    #pragma unroll
    for(int off=32;off;off>>=1){ s+=__shfl_xor(s,off); sq+=__shfl_xor(sq,off); }
    float mean=s*(1.f/192.f), var=sq*(1.f/192.f)-mean*mean;
    float inv=rsqrtf(var+1e-5f);
    short* op=out+(size_t)row*192;
    op[lane]    =bf16rne((v0-mean)*inv*w[lane]    +b[lane]);
    op[lane+64] =bf16rne((v1-mean)*inv*w[lane+64] +b[lane+64]);
    op[lane+128]=bf16rne((v2-mean)*inv*w[lane+128]+b[lane+128]);
  } else {
    int flat=bid-2304;
    int seg=flat/677;
    int i=(flat-seg*677)*256+threadIdx.x;
    const float* src; int size, off;
    switch(seg){
      case 0: src=w0; size=173184; off=0;      break;
      case 1: src=w1; size=110592; off=173184; break;
      case 2: src=w2; size=73728;  off=283776; break;
      case 3: src=w3; size=36864;  off=357504; break;
      case 4: src=w4; size=73728;  off=394368; break;
      case 5: src=w5; size=147456; off=468096; break;
      default:src=w6; size=147456; off=615552; break;
    }
    if(i<size) dst[off+i]=bf16rne(src[i]);
  }
}

// ---------------- merged conv + prep ----------------
__global__ __launch_bounds__(256) void k_convprep(const short* __restrict__ zx, const float* __restrict__ cw,
    const float* __restrict__ cb, short* __restrict__ xbc,
    const float* __restrict__ dt_bias, const float* __restrict__ A_log,
    float* __restrict__ dtb, float* __restrict__ acs, float* __restrict__ csum){
  int bid=blockIdx.x;
  if(bid<2304){
    int idx=bid*256+threadIdx.x;
    int ch0=(idx&63)*8; int rl=idx>>6;
    int l=rl%4608;
    const short* base=zx+(size_t)rl*904+384+ch0;
    short8 x0=*(const short8*)(base);
    short8 x1={0,0,0,0,0,0,0,0},x2=x1,x3=x1;
    if(l>=1) x1=*(const short8*)(base-904);
    if(l>=2) x2=*(const short8*)(base-2*904);
    if(l>=3) x3=*(const short8*)(base-3*904);
    short8 out;
    #pragma unroll
    for(int j=0;j<8;j++){
      float4 w=*(const float4*)(cw+(ch0+j)*4);
      float acc=cb[ch0+j]
        + b2fs(x3[j])*w.x + b2fs(x2[j])*w.y + b2fs(x1[j])*w.z + b2fs(x0[j])*w.w;
      out[j]=bf16rne(siluf_(acc));
    }
    *(short8*)(xbc+(size_t)rl*512+ch0)=out;
  } else {
    int pb=bid-2304;
    int c=pb%36, h=(pb/36)%6, b=pb/216;
    int l=threadIdx.x;
    __shared__ float sb[128];
    if(l<128){
      int row=b*4608+c*128+l;
      float xv=b2fs(zx[(size_t)row*904+896+h])+dt_bias[h];
      float dt=softplusf_(xv);
      dtb[row*6+h]=dt;
      sb[l]=-__expf(A_log[h])*dt;
    }
    __syncthreads();
    for(int off=1;off<128;off<<=1){
      float add=(l>=off && l<128)? sb[l-off]:0.f;
      __syncthreads();
      if(l<128) sb[l]+=add;
      __syncthreads();
    }
    if(l<128){
      acs[((size_t)(b*6+h)*36+c)*128+l]=sb[l];
      if(l==127) csum[(b*6+h)*36+c]=sb[127];
    }
  }
}

// ---------------- fused SSD part A (MFMA): states + diagonal Y (bf16 Y) ----------------
__global__ __launch_bounds__(256) void k_ssd_a(const short* __restrict__ xbc, const float* __restrict__ dtb,
    const float* __restrict__ acs, const float* __restrict__ csum,
    short* __restrict__ st, short* __restrict__ Y){
  int bid=blockIdx.x;
  int h=bid%6, c=(bid/6)%36, b=bid/216;
  __shared__ unsigned short sB[128][68];
  __shared__ unsigned short sC[128][68];
  __shared__ unsigned short sXdT[64][132];
  __shared__ unsigned short sBTE[64][132];
  __shared__ unsigned short sM[128][36];
  __shared__ float sAcs[128];
  __shared__ float sE[128];
  int tid=threadIdx.x;
  int lane=tid&63, wid=tid>>6;
  int m16=lane&15, kq=lane>>4;
  int base_row=b*4608+c*128;
  const float* acsp=acs+((size_t)(b*6+h)*36+c)*128;
  float tot=csum[(b*6+h)*36+c];
  if(tid<128){ float a=acsp[tid]; sAcs[tid]=a; sE[tid]=__expf(tot-a); }
  __syncthreads();
  for(int i=tid;i<1024;i+=256){
    int l=i>>3, n0=(i&7)*8;
    int row=base_row+l;
    const short* rp=xbc+(size_t)row*512;
    short8 Bv=*(const short8*)(rp+384+n0);
    short8 Cv=*(const short8*)(rp+448+n0);
    short8 Xv=*(const short8*)(rp+h*64+n0);
    float dt=dtb[row*6+h];
    float e=sE[l];
    *(short8*)&sB[l][n0]=Bv;
    *(short8*)&sC[l][n0]=Cv;
    #pragma unroll
    for(int j=0;j<8;j++){
      sXdT[n0+j][l]=bf16u(b2fs(Xv[j])*dt);
      sBTE[n0+j][l]=bf16u(b2fs(Bv[j])*e);
    }
  }
  __syncthreads();
  {
    int wr=wid>>1, wc=wid&1;
    f32x4 accS[2][2];
    #pragma unroll
    for(int mi=0;mi<2;mi++)
      #pragma unroll
      for(int ni=0;ni<2;ni++) accS[mi][ni]=(f32x4){0.f,0.f,0.f,0.f};
    #pragma unroll
    for(int ks=0;ks<4;ks++){
      short8 a0=*(const short8*)&sXdT[wr*32+m16][ks*32+kq*8];
      short8 a1=*(const short8*)&sXdT[wr*32+16+m16][ks*32+kq*8];
      short8 b0=*(const short8*)&sBTE[wc*32+m16][ks*32+kq*8];
      short8 b1=*(const short8*)&sBTE[wc*32+16+m16][ks*32+kq*8];
      accS[0][0]=__builtin_amdgcn_mfma_f32_16x16x32_bf16(a0,b0,accS[0][0],0,0,0);
      accS[0][1]=__builtin_amdgcn_mfma_f32_16x16x32_bf16(a0,b1,accS[0][1],0,0,0);
      accS[1][0]=__builtin_amdgcn_mfma_f32_16x16x32_bf16(a1,b0,accS[1][0],0,0,0);
      accS[1][1]=__builtin_amdgcn_mfma_f32_16x16x32_bf16(a1,b1,accS[1][1],0,0,0);
    }
    short* op=st+((size_t)((b*36+c)*6+h))*4096;
    #pragma unroll
    for(int mi=0;mi<2;mi++)
      #pragma unroll
      for(int ni=0;ni<2;ni++)
        #pragma unroll
        for(int r=0;r<4;r++){
          int p=wr*32+mi*16+4*kq+r, n=wc*32+ni*16+m16;
          op[p*64+n]=bf16rne(accS[mi][ni][r]);
        }
  }
  #pragma unroll
  for(int ti=0;ti<2;ti++){
    int t = ti? (7-wid) : wid;
    f32x4 accY[4];
    #pragma unroll
    for(int pi=0;pi<4;pi++) accY[pi]=(f32x4){0.f,0.f,0.f,0.f};
    int nslab=(t>>1)+1;
    for(int jt=0;jt<nslab;jt++){
      f32x4 accD[2];
      accD[0]=(f32x4){0.f,0.f,0.f,0.f}; accD[1]=(f32x4){0.f,0.f,0.f,0.f};
      #pragma unroll
      for(int ks=0;ks<2;ks++){
        short8 a =*(const short8*)&sC[t*16+m16][ks*32+kq*8];
        short8 b0=*(const short8*)&sB[jt*32+m16][ks*32+kq*8];
        short8 b1=*(const short8*)&sB[jt*32+16+m16][ks*32+kq*8];
        accD[0]=__builtin_amdgcn_mfma_f32_16x16x32_bf16(a,b0,accD[0],0,0,0);
        accD[1]=__builtin_amdgcn_mfma_f32_16x16x32_bf16(a,b1,accD[1],0,0,0);
      }
      int lrow=t*16+4*kq;
      #pragma unroll
      for(int sti=0;sti<2;sti++)
        #pragma unroll
        for(int r=0;r<4;r++){
          int l=lrow+r, s=jt*32+sti*16+m16;
          float v=(s<=l)? __expf(sAcs[l]-sAcs[s])*accD[sti][r] : 0.f;
          sM[l][sti*16+m16]=bf16u(v);
        }
      short8 am=*(const short8*)&sM[t*16+m16][kq*8];
      #pragma unroll
      for(int pi=0;pi<4;pi++){
        short8 bx=*(const short8*)&sXdT[pi*16+m16][jt*32+kq*8];
        accY[pi]=__builtin_amdgcn_mfma_f32_16x16x32_bf16(am,bx,accY[pi],0,0,0);
      }
    }
    #pragma unroll
    for(int pi=0;pi<4;pi++)
      #pragma unroll
      for(int r=0;r<4;r++){
        int l=t*16+4*kq+r, p=pi*16+m16;
        Y[(size_t)(base_row+l)*384+h*64+p]=bf16rne(accY[pi][r]);
      }
  }
}

// ---------------- sequential chunk scan (all 36 loads batched) ----------------
__global__ __launch_bounds__(256) void k_scan(const short* __restrict__ st, const float* __restrict__ csum,
                                              short* __restrict__ prevb){
  int bid=blockIdx.x;
  int seg=bid&15, bh=bid>>4;
  int b=bh/6, h=bh%6;
  __shared__ float sE[36];
  if(threadIdx.x<36) sE[threadIdx.x]=__expf(csum[(b*6+h)*36+threadIdx.x]);
  __syncthreads();
  int e=seg*256+threadIdx.x;
  size_t stride=(size_t)6*4096;
  size_t idx=((size_t)((b*36+0)*6+h))*4096+e;
  float v[36];
  #pragma unroll
  for(int j=0;j<36;j++) v[j]=b2fs(st[idx+j*stride]);   // 36 independent loads in flight
  float carry=0.f;
  #pragma unroll
  for(int j=0;j<36;j++){
    prevb[idx+j*stride]=bf16rne(carry);
    carry=carry*sE[j]+v[j];
  }
}

// ---------------- SSD part B (MFMA) ----------------
__global__ __launch_bounds__(256) void k_ssd_b(const short* __restrict__ xbc, const short* __restrict__ prevb,
    const float* __restrict__ acs, const float* __restrict__ Dv, short* __restrict__ Y){
  int bid=blockIdx.x;
  int h=bid%6, c=(bid/6)%36, b=bid/216;
  __shared__ unsigned short sC[128][68];
  __shared__ unsigned short sP[64][68];
  __shared__ float sAcs[128];
  int tid=threadIdx.x;
  int lane=tid&63, wid=tid>>6;
  int m16=lane&15, kq=lane>>4;
  int base_row=b*4608+c*128;
  const float* acsp=acs+((size_t)(b*6+h)*36+c)*128;
  if(tid<128) sAcs[tid]=acsp[tid];
  for(int i=tid;i<1024;i+=256){
    int l=i>>3, n0=(i&7)*8;
    short8 Cv=*(const short8*)(xbc+(size_t)(base_row+l)*512+448+n0);
    *(short8*)&sC[l][n0]=Cv;
  }
  const short* pp=prevb+((size_t)((b*36+c)*6+h))*4096;
  for(int i=tid;i<512;i+=256){
    int p_=i>>3, n0=(i&7)*8;
    short8 Pv=*(const short8*)(pp+p_*64+n0);
    *(short8*)&sP[p_][n0]=Pv;
  }
  __syncthreads();
  float Dh=Dv[h];
  int lt0=2*wid;
  f32x4 acc[2][4];
  #pragma unroll
  for(int li=0;li<2;li++)
    #pragma unroll
    for(int pi=0;pi<4;pi++) acc[li][pi]=(f32x4){0.f,0.f,0.f,0.f};
  #pragma unroll
  for(int ks=0;ks<2;ks++){
    short8 a0=*(const short8*)&sC[lt0*16+m16][ks*32+kq*8];
    short8 a1=*(const short8*)&sC[(lt0+1)*16+m16][ks*32+kq*8];
    #pragma unroll
    for(int pi=0;pi<4;pi++){
      short8 bp=*(const short8*)&sP[pi*16+m16][ks*32+kq*8];
      acc[0][pi]=__builtin_amdgcn_mfma_f32_16x16x32_bf16(a0,bp,acc[0][pi],0,0,0);
      acc[1][pi]=__builtin_amdgcn_mfma_f32_16x16x32_bf16(a1,bp,acc[1][pi],0,0,0);
    }
  }
  #pragma unroll
  for(int li=0;li<2;li++){
    #pragma unroll
    for(int r=0;r<4;r++){
      int l=(lt0+li)*16+4*kq+r;
      int row=base_row+l;
      float e=__expf(sAcs[l]);
      #pragma unroll
      for(int pi=0;pi<4;pi++){
        int p=pi*16+m16;
        size_t yi=(size_t)row*384+h*64+p;
        float xpv=b2fs(xbc[(size_t)row*512+h*64+p]);
        Y[yi]=bf16rne(b2fs(Y[yi])+acc[li][pi][r]*e+xpv*Dh);
      }
    }
  }
}

// ---------------- rmsgate (+ zero ECA partial) ----------------
__global__ __launch_bounds__(256) void k_rmsgate(const short* __restrict__ Y, const short* __restrict__ zx,
    const float* __restrict__ nw, short* __restrict__ yn, float* __restrict__ partial){
  if(blockIdx.x<3){
    int t=blockIdx.x*256+threadIdx.x;
    if(t<768) partial[t]=0.f;
  }
  int warp=threadIdx.x>>6, lane=threadIdx.x&63;
  int row=blockIdx.x*4+warp;
  float v[6]; float ss=0.f;
  #pragma unroll
  for(int j=0;j<6;j++){
    int cidx=lane+64*j;
    float y=b2fs(Y[(size_t)row*384+cidx]);
    float z=b2fs(zx[(size_t)row*904+cidx]);
    y*=siluf_(z);
    v[j]=y; ss+=y*y;
  }
  #pragma unroll
  for(int off=32;off;off>>=1) ss+=__shfl_xor(ss,off);
  float sc=rsqrtf(ss*(1.f/384.f)+1e-5f);
  #pragma unroll
  for(int j=0;j<6;j++){
    int cidx=lane+64*j;
    yn[(size_t)row*384+cidx]=bf16rne(v[j]*sc*nw[cidx]);
  }
}

// ---------------- windowed attention, split-K over 2 half-waves (128 thr/block) ----------------
__global__ __launch_bounds__(128) void k_att2(const short* __restrict__ qkv, const short* __restrict__ xn,
    const float* __restrict__ gw, const float* __restrict__ gb, short* __restrict__ obuf){
  int bid=blockIdx.x;
  int widx=bid/6, head=bid-widx*6;
  int b=widx/36, t=widx-b*36;
  int wi=t/6, wj=t-wi*6;
  int n=threadIdx.x&63, half=threadIdx.x>>6;
  __shared__ float sK[64][32], sV[64][32];
  __shared__ float sO2[64][32];
  __shared__ float sM2[64], sD2[64];
  const short* qp=qkv+(size_t)(widx*64+n)*576+head*32;
  float q[32];
  {
    short8 v0=*(const short8*)(qp),    v1=*(const short8*)(qp+8);
    short8 v2=*(const short8*)(qp+16), v3=*(const short8*)(qp+24);
    #pragma unroll
    for(int i=0;i<8;i++){ q[i]=b2fs(v0[i]); q[8+i]=b2fs(v1[i]); q[16+i]=b2fs(v2[i]); q[24+i]=b2fs(v3[i]); }
    short8 k0=*(const short8*)(qp+192+half*16), k1=*(const short8*)(qp+200+half*16);
    short8 u0=*(const short8*)(qp+384+half*16), u1=*(const short8*)(qp+392+half*16);
    #pragma unroll
    for(int i=0;i<8;i++){
      sK[n][half*16+i]=b2fs(k0[i]); sK[n][half*16+8+i]=b2fs(k1[i]);
      sV[n][half*16+i]=b2fs(u0[i]); sV[n][half*16+8+i]=b2fs(u1[i]);
    }
  }
  int h2=wi*8+(n>>3), w2=wj*8+(n&7);
  int rh=(h2<40)?0:((h2<44)?1:2);
  int rw=(w2<40)?0:((w2<44)?1:2);
  int myid=rh*3+rw;
  __syncthreads();
  const float scale=0.17677669529663687f;
  float p[32]; float mx=-1e30f;
  #pragma unroll 4
  for(int jj=0;jj<32;jj++){
    int j=half*32+jj;
    float sc=0;
    #pragma unroll
    for(int d=0;d<32;d++) sc+=q[d]*sK[j][d];
    int hj=wi*8+(j>>3), wjj=wj*8+(j&7);
    int rhj=(hj<40)?0:((hj<44)?1:2);
    int rwj=(wjj<40)?0:((wjj<44)?1:2);
    float m=((rhj*3+rwj)!=myid)? -100.f:0.f;
    float v=sc*scale+m;
    p[jj]=v; mx=fmaxf(mx,v);
  }
  float den=0;
  #pragma unroll
  for(int jj=0;jj<32;jj++){ p[jj]=__expf(p[jj]-mx); den+=p[jj]; }
  float o[32];
  #pragma unroll
  for(int d=0;d<32;d++) o[d]=0.f;
  #pragma unroll 4
  for(int jj=0;jj<32;jj++){
    float pj=p[jj];
    #pragma unroll
    for(int d=0;d<32;d++) o[d]+=pj*sV[half*32+jj][d];
  }
  if(half==1){
    sM2[n]=mx; sD2[n]=den;
    #pragma unroll
    for(int d=0;d<32;d++) sO2[n][d]=o[d];
  }
  __syncthreads();
  if(half==0){
    float m1=sM2[n], d1=sD2[n];
    float m=fmaxf(mx,m1);
    float e0=__expf(mx-m), e1=__expf(m1-m);
    float dent=den*e0+d1*e1;
    int xrow=map_row(widx*64+n,2);
    const short* xp=xn+(size_t)xrow*192;
    const float* gwp=gw+head*192;
    float g=0;
    #pragma unroll
    for(int c=0;c<24;c++){
      short8 xv=*(const short8*)(xp+c*8);
      float4 w0=*(const float4*)(gwp+c*8);
      float4 w1=*(const float4*)(gwp+c*8+4);
      g+=b2fs(xv[0])*w0.x+b2fs(xv[1])*w0.y+b2fs(xv[2])*w0.z+b2fs(xv[3])*w0.w
        +b2fs(xv[4])*w1.x+b2fs(xv[5])*w1.y+b2fs(xv[6])*w1.z+b2fs(xv[7])*w1.w;
    }
    g=sigmoidf_(g+gb[head]);
    float fac=g/dent;
    short* op=obuf+(size_t)(widx*64+n)*192+head*32;
    #pragma unroll
    for(int v8=0;v8<4;v8++){
      short8 w;
      #pragma unroll
      for(int j=0;j<8;j++){
        int d=v8*8+j;
        w[j]=bf16rne((o[d]*e0+sO2[n][d]*e1)*fac);
      }
      *(short8*)(op+v8*8)=w;
    }
  }
}

// ---------------- fused: xo = x + xf*ca(partial), then LayerNorm(xo) -> bf16 ----------------
__global__ __launch_bounds__(256) void k_xoln(const float* __restrict__ x, const float* __restrict__ xf,
    const float* __restrict__ partial, const float* __restrict__ ecaw,
    const float* __restrict__ w, const float* __restrict__ bvec,
    float* __restrict__ xo, short* __restrict__ out){
  int warp=threadIdx.x>>6, lane=threadIdx.x&63;
  int row=blockIdx.x*4+warp;
  int bidx=row/2304;
  const float* pp=partial+bidx*192;
  float e0=ecaw[0], e1=ecaw[1], e2=ecaw[2];
  auto cav=[&](int c)->float{
    float pv=pp[c];
    float lft=(c>0)?   pp[c-1]:0.f;
    float rgt=(c<191)? pp[c+1]:0.f;
    return sigmoidf_((e0*lft+e1*pv+e2*rgt)*(1.f/2304.f));
  };
  const float* xp=x+(size_t)row*192;
  const float* fp=xf+(size_t)row*192;
  float v0=xp[lane]    +fp[lane]    *cav(lane);
  float v1=xp[lane+64] +fp[lane+64] *cav(lane+64);
  float v2=xp[lane+128]+fp[lane+128]*cav(lane+128);
  float* op=xo+(size_t)row*192;
  op[lane]=v0; op[lane+64]=v1; op[lane+128]=v2;
  float s=v0+v1+v2, sq=v0*v0+v1*v1+v2*v2;
  #pragma unroll
  for(int off=32;off;off>>=1){ s+=__shfl_xor(s,off); sq+=__shfl_xor(sq,off); }
  float mean=s*(1.f/192.f), var=sq*(1.f/192.f)-mean*mean;
  float inv=rsqrtf(var+1e-5f);
  short* bp=out+(size_t)row*192;
  bp[lane]    =bf16rne((v0-mean)*inv*w[lane]    +bvec[lane]);
  bp[lane+64] =bf16rne((v1-mean)*inv*w[lane+64] +bvec[lane+64]);
  bp[lane+128]=bf16rne((v2-mean)*inv*w[lane+128]+bvec[lane+128]);
}

extern "C" void kernel_launch(void* const* d_in, const int* in_sizes, int n_in,
                              void* d_out, int out_size, void* d_ws, size_t ws_size,
                              hipStream_t stream){
  const float* x     =(const float*)d_in[0];
  const float* n1w   =(const float*)d_in[3];
  const float* n1b   =(const float*)d_in[4];
  const float* m_in_w=(const float*)d_in[5];
  const float* m_cw  =(const float*)d_in[6];
  const float* m_cb  =(const float*)d_in[7];
  const float* m_dtb =(const float*)d_in[8];
  const float* m_Al  =(const float*)d_in[9];
  const float* m_D   =(const float*)d_in[10];
  const float* m_nw  =(const float*)d_in[11];
  const float* m_ow  =(const float*)d_in[12];
  const float* qkvw  =(const float*)d_in[13];
  const float* qkvb  =(const float*)d_in[14];
  const float* projw =(const float*)d_in[15];
  const float* projb =(const float*)d_in[16];
  const float* gatew =(const float*)d_in[17];
  const float* gateb =(const float*)d_in[18];
  const float* fusw  =(const float*)d_in[19];
  const float* fusb  =(const float*)d_in[20];
  const float* ecaw  =(const float*)d_in[21];
  const float* n2w   =(const float*)d_in[22];
  const float* n2b   =(const float*)d_in[23];
  const float* fc1w  =(const float*)d_in[24];
  const float* fc1b  =(const float*)d_in[25];
  const float* fc2w  =(const float*)d_in[26];
  const float* fc2b  =(const float*)d_in[27];
  float* out=(float*)d_out;
  float* ws=(float*)d_ws;

  // arena (float offsets); bf16 buffers as short* aliases; zx stride = 904
  short* xn_bf  = (short*)(ws + 0);        //   884,736 fl [LN1 .. att2]
  short* wb     = (short*)(ws + 884736);   //   381,504 fl persistent
  short* zx_bf  = (short*)(ws + 1266240);  // 4,165,632 fl (9216x904) [in_proj .. rmsgate]
  short* xbc_bf = (short*)(ws + 5431872);  // 2,359,296 fl [conv .. ssd_b]
  float* dtb    = ws + 7791168;            //    55,296
  float* acs    = ws + 7846464;            //    55,296
  float* csum   = ws + 7901760;            //       512
  short* st_bf  = (short*)(ws + 7902272);  // 1,769,472 fl [ssd_a .. scan]
  short* prevb_bf=(short*)(ws + 9671744);  // 1,769,472 fl [scan .. ssd_b]
  short* Y_bf   = (short*)(ws + 11441216); // region 3,538,944 fl [ssd_a .. rmsgate]
  float* bigbf  = ws + 14980160;           // 3,538,944   (yn | h1 bf16)
  short* qkv_bf = (short*)(ws + 18519104); // 2,654,208 fl [inqkv .. att2]
  short* obuf_bf= (short*)(ws + 21173312); //   884,736 fl [att2 .. opproj]
  // aliases (disjoint lifetimes)
  short* hbuf_bf= xn_bf;                   // [xoln .. fc1]
  short* xcat_bf= prevb_bf;                // [opproj .. fusion]
  float* xf     = (float*)st_bf;           // [fusion .. xoln]
  float* xo     = (float*)Y_bf;            // [xoln .. fc2]
  short* yn_bf  = (short*)bigbf;           // [rmsgate .. opproj]
  short* h1_bf  = (short*)bigbf;           // [fc1 .. fc2]
  float* partial= dtb;                     // ECA sums [rmsgate .. xoln]
  // bf16 weight segments
  short* wb_in  = wb + 0;
  short* wb_qkv = wb + 173184;
  short* wb_out = wb + 283776;
  short* wb_proj= wb + 357504;
  short* wb_fus = wb + 394368;
  short* wb_fc1 = wb + 468096;
  short* wb_fc2 = wb + 615552;

  // 1. LN1 + weight convert
  k_lnw2b<<<7043,256,0,stream>>>(x,n1w,n1b,xn_bf, m_in_w,qkvw,m_ow,projw,fusw,fc1w,fc2w,wb);
  // 2. in_proj + qkv
  k_gemm_inqkv<<<dim3(144,24),256,32768,stream>>>(xn_bf,wb_in,zx_bf,wb_qkv,qkvb,qkv_bf);
  // 3. attention (only depends on qkv; own buffer)
  k_att2<<<864,128,0,stream>>>(qkv_bf,xn_bf,gatew,gateb,obuf_bf);
  // 4. conv + prep
  k_convprep<<<2736,256,0,stream>>>(zx_bf,m_cw,m_cb,xbc_bf, m_dtb,m_Al,dtb,acs,csum);
  // 5. SSD part A
  k_ssd_a<<<432,256,0,stream>>>(xbc_bf,dtb,acs,csum,st_bf,Y_bf);
  // 6. chunk scan
  k_scan<<<192,256,0,stream>>>(st_bf,csum,prevb_bf);
  // 7. SSD part B
  k_ssd_b<<<432,256,0,stream>>>(xbc_bf,prevb_bf,acs,m_D,Y_bf);
  // 8. gated RMS norm (+ zero partial)
  k_rmsgate<<<2304,256,0,stream>>>(Y_bf,zx_bf,m_nw,yn_bf,partial);
  // 9. mamba out_proj + attn proj -> xcat (merged)
  k_gemm_opproj<<<dim3(144,6),256,32768,stream>>>(yn_bf,wb_out,obuf_bf,wb_proj,projb,xcat_bf);
  // 10. fusion -> xf fp32 + ECA pooling
  k_gemm<384><<<dim3(144,3),256,32768,stream>>>(xcat_bf,wb_fus,fusb,nullptr,xf,nullptr, 192,192,0, 0,0,0, partial);
  // 11. fused xo + ECA sigmoid + LN2
  k_xoln<<<2304,256,0,stream>>>(x,xf,partial,ecaw,n2w,n2b,xo,hbuf_bf);
  // 12. fc1 + gelu
  k_gemm<192><<<dim3(144,12),256,32768,stream>>>(hbuf_bf,wb_fc1,fc1b,nullptr,nullptr,h1_bf, 768,768,0, 0,0,2, nullptr);
  // 13. fc2 + residual -> out
  k_gemm<768><<<dim3(144,3),256,32768,stream>>>(h1_bf,wb_fc2,fc2b,xo,out,nullptr, 192,192,0, 0,0,3, nullptr);
}

// Round 18
// 169.183 us; speedup vs baseline: 1.0188x; 1.0188x over previous
//
#include <hip/hip_runtime.h>
#include <math.h>

#define DEV __device__ __forceinline__

typedef __attribute__((ext_vector_type(8))) short short8;
typedef __attribute__((ext_vector_type(4))) float f32x4;

DEV float sigmoidf_(float x){ return 1.f/(1.f+__expf(-x)); }
DEV float siluf_(float x){ return x/(1.f+__expf(-x)); }
DEV float softplusf_(float x){ return (x>20.f)? x : log1pf(__expf(x)); }

DEV short bf16rne(float f){
  unsigned u=__float_as_uint(f);
  unsigned r=(u + 0x7FFFu + ((u>>16)&1u))>>16;
  return (short)r;
}
DEV unsigned short bf16u(float f){ return (unsigned short)bf16rne(f); }
DEV float b2f(unsigned short u){ return __uint_as_float(((unsigned)u)<<16); }
DEV float b2fs(short u){ return __uint_as_float(((unsigned)(unsigned short)u)<<16); }

// async global->LDS, 16B per lane
DEV void gll16(const void* g, void* l){
  __builtin_amdgcn_global_load_lds(
      (const __attribute__((address_space(1))) void*)g,
      (__attribute__((address_space(3))) void*)(unsigned)(uintptr_t)l,
      16, 0, 0);
}

// row remap: 0 identity; 1 mamba interleave; 2 shifted-window gather
DEV int map_row(int r, int mode){
  if(mode==1){
    int b=r/4608; int gl=r-b*4608;
    return ((gl&1)*2+b)*2304 + (gl>>1);
  }
  if(mode==2){
    int widx=r>>6, n=r&63;
    int b=widx/36, t=widx-b*36;
    int wi=t/6, wj=t-wi*6;
    int h2=wi*8+(n>>3), w2=wj*8+(n&7);
    int ho=h2+4; if(ho>=48) ho-=48;
    int wo=w2+4; if(wo>=48) wo-=48;
    return b*2304 + ho*48 + wo;
  }
  return r;
}

// ================= unified double-buffered bf16 MFMA GEMM body (static 32KB LDS) =================
template<int K>
DEV void gemm_body(const short* __restrict__ A, const short* __restrict__ W,
    const float* __restrict__ bias, const float* __restrict__ res,
    float* __restrict__ Of, short* __restrict__ Ob,
    int N, int ldo, int col_off, int gmode, int smode, int epi,
    int bx, int by, float* __restrict__ pool){
  constexpr int NP=K/64;
  __shared__ short sMem[16384];                    // 32 KB
  short (*sA)[64][64]=(short(*)[64][64])sMem;
  short (*sB)[64][64]=(short(*)[64][64])(sMem+8192);
  float* sO=(float*)sMem;
  int tid=threadIdx.x, lane=tid&63, wid=tid>>6;
  int m16=lane&15, kq=lane>>4;
  int bm=bx*64, bn=by*64;
  int lrow=lane>>3;
  int lcol=((lane&7)^lrow)<<3;
  int sx=(m16&7)<<3;
  const short* ap[2]; const short* wp[2];
  #pragma unroll
  for(int t=0;t<2;t++){
    int i8=wid+t*4;
    int arow=map_row(bm+i8*8+lrow,gmode);
    ap[t]=A+(size_t)arow*K+lcol;
    int n=bn+i8*8+lrow;
    if(n>=N) n=N-1;                                // clamp: finite garbage, masked at store
    wp[t]=W+(size_t)n*K+lcol;
  }
  f32x4 acc[4];
  #pragma unroll
  for(int ni=0;ni<4;ni++) acc[ni]=(f32x4){0.f,0.f,0.f,0.f};

  auto stage=[&](int p,int b){
    #pragma unroll
    for(int t=0;t<2;t++){
      int i8=wid+t*4;
      gll16(ap[t]+p*64, &sA[b][i8*8][0]);
      gll16(wp[t]+p*64, &sB[b][i8*8][0]);
    }
  };
  auto compute=[&](int p,int b){
    __builtin_amdgcn_s_setprio(1);
    #pragma unroll
    for(int half=0;half<2;half++){
      int k2=(half*32 + kq*8) ^ sx;
      short8 af=*(const short8*)&sA[b][wid*16+m16][k2];
      #pragma unroll
      for(int ni=0;ni<4;ni++){
        short8 bf=*(const short8*)&sB[b][ni*16+m16][k2];
        acc[ni]=__builtin_amdgcn_mfma_f32_16x16x32_bf16(af,bf,acc[ni],0,0,0);
      }
    }
    __builtin_amdgcn_s_setprio(0);
  };

  stage(0,0);
  if(NP>1) stage(1,1);
  #pragma unroll
  for(int p=0;p<NP;p++){
    if(p+1<NP) asm volatile("s_waitcnt vmcnt(4)":::"memory");
    else       asm volatile("s_waitcnt vmcnt(0)":::"memory");
    __builtin_amdgcn_s_barrier();
    compute(p,p&1);
    if(p+2<NP){
      __builtin_amdgcn_s_barrier();
      stage(p+2,p&1);
    }
  }

  __syncthreads();
  {
    int mbase=wid*16+4*kq;
    #pragma unroll
    for(int ni=0;ni<4;ni++)
      #pragma unroll
      for(int r=0;r<4;r++)
        sO[(mbase+r)*65 + ni*16+m16]=acc[ni][r];
  }
  __syncthreads();
  int erow=tid>>3, c0=(tid&7)*8;
  #pragma unroll
  for(int rd=0;rd<2;rd++){
    int ml=rd*32+erow;
    int m=bm+ml;
    int orow=map_row(m,smode);
    float v[8];
    #pragma unroll
    for(int j=0;j<8;j++) v[j]=sO[ml*65+c0+j];
    const float* rp=res? res+(size_t)orow*ldo+col_off : nullptr;
    #pragma unroll
    for(int j=0;j<8;j++){
      int nn=bn+c0+j;
      float val=v[j];
      if(bias && nn<N) val+=bias[nn];
      if(epi==2) val=0.5f*val*(1.f+erff(val*0.70710678118654752f));
      else if(epi==3) val+=rp[nn];
      v[j]=val;
    }
    size_t obase=(size_t)orow*ldo+col_off+bn+c0;
    if(bn+c0+7<N){
      if(Ob){
        short8 w;
        #pragma unroll
        for(int j=0;j<8;j++) w[j]=bf16rne(v[j]);
        *(short8*)(Ob+obase)=w;
      } else {
        float4 f0={v[0],v[1],v[2],v[3]}, f1={v[4],v[5],v[6],v[7]};
        *(float4*)(Of+obase)=f0;
        *(float4*)(Of+obase+4)=f1;
      }
    } else {
      #pragma unroll
      for(int j=0;j<8;j++){
        int nn=bn+c0+j;
        if(nn<N){ if(Ob) Ob[obase+j]=bf16rne(v[j]); else Of[obase+j]=v[j]; }
      }
    }
  }
  if(pool){
    if(tid<64){
      float s=0;
      #pragma unroll 8
      for(int ml=0;ml<64;ml++) s+=sO[ml*65+tid];
      if(bias) s+=64.f*bias[bn+tid];
      atomicAdd(&pool[(bm/2304)*192 + bn+tid], s);
    }
  }
}

template<int K>
__global__ __launch_bounds__(256,4) void k_gemm(const short* __restrict__ A, const short* __restrict__ W,
    const float* __restrict__ bias, const float* __restrict__ res,
    float* __restrict__ Of, short* __restrict__ Ob,
    int N, int ldo, int col_off, int gmode, int smode, int epi, float* __restrict__ pool){
  gemm_body<K>(A,W,bias,res,Of,Ob,N,ldo,col_off,gmode,smode,epi,blockIdx.x,blockIdx.y,pool);
}

// merged in_proj + qkv: single call site -> single 32KB LDS
__global__ __launch_bounds__(256,4) void k_gemm_inqkv(const short* __restrict__ xn,
    const short* __restrict__ w_in, short* __restrict__ zx,
    const short* __restrict__ w_qkv, const float* __restrict__ qkvb, short* __restrict__ qkv){
  int by=blockIdx.y;
  const short* W; short* O; const float* bias; int N,ldo,gm,byy;
  if(by<15){ W=w_in;  O=zx;  bias=nullptr; N=902; ldo=904; gm=1; byy=by; }
  else     { W=w_qkv; O=qkv; bias=qkvb;    N=576; ldo=576; gm=2; byy=by-15; }
  gemm_body<192>(xn,W,bias,nullptr,nullptr,O, N,ldo,0, gm,0,0, blockIdx.x,byy, nullptr);
}

// ---------------- merged LayerNorm1 + weight bf16 pre-convert ----------------
__global__ __launch_bounds__(256) void k_lnw2b(const float* __restrict__ in, const float* __restrict__ w,
    const float* __restrict__ b, short* __restrict__ out,
    const float* __restrict__ w0,const float* __restrict__ w1,const float* __restrict__ w2,
    const float* __restrict__ w3,const float* __restrict__ w4,const float* __restrict__ w5,
    const float* __restrict__ w6, short* __restrict__ dst){
  int bid=blockIdx.x;
  if(bid<2304){
    int warp=threadIdx.x>>6, lane=threadIdx.x&63;
    int row=bid*4+warp;
    const float* ip=in+(size_t)row*192;
    float v0=ip[lane], v1=ip[lane+64], v2=ip[lane+128];
    float s=v0+v1+v2, sq=v0*v0+v1*v1+v2*v2;
    #pragma unroll
    for(int off=32;off;off>>=1){ s+=__shfl_xor(s,off); sq+=__shfl_xor(sq,off); }
    float mean=s*(1.f/192.f), var=sq*(1.f/192.f)-mean*mean;
    float inv=rsqrtf(var+1e-5f);
    short* op=out+(size_t)row*192;
    op[lane]    =bf16rne((v0-mean)*inv*w[lane]    +b[lane]);
    op[lane+64] =bf16rne((v1-mean)*inv*w[lane+64] +b[lane+64]);
    op[lane+128]=bf16rne((v2-mean)*inv*w[lane+128]+b[lane+128]);
  } else {
    int flat=bid-2304;
    int seg=flat/677;
    int i=(flat-seg*677)*256+threadIdx.x;
    const float* src; int size, off;
    switch(seg){
      case 0: src=w0; size=173184; off=0;      break;
      case 1: src=w1; size=110592; off=173184; break;
      case 2: src=w2; size=73728;  off=283776; break;
      case 3: src=w3; size=36864;  off=357504; break;
      case 4: src=w4; size=73728;  off=394368; break;
      case 5: src=w5; size=147456; off=468096; break;
      default:src=w6; size=147456; off=615552; break;
    }
    if(i<size) dst[off+i]=bf16rne(src[i]);
  }
}

// ---------------- merged conv + prep ----------------
__global__ __launch_bounds__(256) void k_convprep(const short* __restrict__ zx, const float* __restrict__ cw,
    const float* __restrict__ cb, short* __restrict__ xbc,
    const float* __restrict__ dt_bias, const float* __restrict__ A_log,
    float* __restrict__ dtb, float* __restrict__ acs, float* __restrict__ csum){
  int bid=blockIdx.x;
  if(bid<2304){
    int idx=bid*256+threadIdx.x;
    int ch0=(idx&63)*8; int rl=idx>>6;
    int l=rl%4608;
    const short* base=zx+(size_t)rl*904+384+ch0;
    short8 x0=*(const short8*)(base);
    short8 x1={0,0,0,0,0,0,0,0},x2=x1,x3=x1;
    if(l>=1) x1=*(const short8*)(base-904);
    if(l>=2) x2=*(const short8*)(base-2*904);
    if(l>=3) x3=*(const short8*)(base-3*904);
    short8 out;
    #pragma unroll
    for(int j=0;j<8;j++){
      float4 w=*(const float4*)(cw+(ch0+j)*4);
      float acc=cb[ch0+j]
        + b2fs(x3[j])*w.x + b2fs(x2[j])*w.y + b2fs(x1[j])*w.z + b2fs(x0[j])*w.w;
      out[j]=bf16rne(siluf_(acc));
    }
    *(short8*)(xbc+(size_t)rl*512+ch0)=out;
  } else {
    int pb=bid-2304;
    int c=pb%36, h=(pb/36)%6, b=pb/216;
    int l=threadIdx.x;
    __shared__ float sb[128];
    if(l<128){
      int row=b*4608+c*128+l;
      float xv=b2fs(zx[(size_t)row*904+896+h])+dt_bias[h];
      float dt=softplusf_(xv);
      dtb[row*6+h]=dt;
      sb[l]=-__expf(A_log[h])*dt;
    }
    __syncthreads();
    for(int off=1;off<128;off<<=1){
      float add=(l>=off && l<128)? sb[l-off]:0.f;
      __syncthreads();
      if(l<128) sb[l]+=add;
      __syncthreads();
    }
    if(l<128){
      acs[((size_t)(b*6+h)*36+c)*128+l]=sb[l];
      if(l==127) csum[(b*6+h)*36+c]=sb[127];
    }
  }
}

// ---------------- fused SSD part A (MFMA): states + diagonal Y (bf16 Y) ----------------
__global__ __launch_bounds__(256) void k_ssd_a(const short* __restrict__ xbc, const float* __restrict__ dtb,
    const float* __restrict__ acs, const float* __restrict__ csum,
    short* __restrict__ st, short* __restrict__ Y){
  int bid=blockIdx.x;
  int h=bid%6, c=(bid/6)%36, b=bid/216;
  __shared__ unsigned short sB[128][68];
  __shared__ unsigned short sC[128][68];
  __shared__ unsigned short sXdT[64][132];
  __shared__ unsigned short sBTE[64][132];
  __shared__ unsigned short sM[128][36];
  __shared__ float sAcs[128];
  __shared__ float sE[128];
  int tid=threadIdx.x;
  int lane=tid&63, wid=tid>>6;
  int m16=lane&15, kq=lane>>4;
  int base_row=b*4608+c*128;
  const float* acsp=acs+((size_t)(b*6+h)*36+c)*128;
  float tot=csum[(b*6+h)*36+c];
  if(tid<128){ float a=acsp[tid]; sAcs[tid]=a; sE[tid]=__expf(tot-a); }
  __syncthreads();
  for(int i=tid;i<1024;i+=256){
    int l=i>>3, n0=(i&7)*8;
    int row=base_row+l;
    const short* rp=xbc+(size_t)row*512;
    short8 Bv=*(const short8*)(rp+384+n0);
    short8 Cv=*(const short8*)(rp+448+n0);
    short8 Xv=*(const short8*)(rp+h*64+n0);
    float dt=dtb[row*6+h];
    float e=sE[l];
    *(short8*)&sB[l][n0]=Bv;
    *(short8*)&sC[l][n0]=Cv;
    #pragma unroll
    for(int j=0;j<8;j++){
      sXdT[n0+j][l]=bf16u(b2fs(Xv[j])*dt);
      sBTE[n0+j][l]=bf16u(b2fs(Bv[j])*e);
    }
  }
  __syncthreads();
  {
    int wr=wid>>1, wc=wid&1;
    f32x4 accS[2][2];
    #pragma unroll
    for(int mi=0;mi<2;mi++)
      #pragma unroll
      for(int ni=0;ni<2;ni++) accS[mi][ni]=(f32x4){0.f,0.f,0.f,0.f};
    #pragma unroll
    for(int ks=0;ks<4;ks++){
      short8 a0=*(const short8*)&sXdT[wr*32+m16][ks*32+kq*8];
      short8 a1=*(const short8*)&sXdT[wr*32+16+m16][ks*32+kq*8];
      short8 b0=*(const short8*)&sBTE[wc*32+m16][ks*32+kq*8];
      short8 b1=*(const short8*)&sBTE[wc*32+16+m16][ks*32+kq*8];
      accS[0][0]=__builtin_amdgcn_mfma_f32_16x16x32_bf16(a0,b0,accS[0][0],0,0,0);
      accS[0][1]=__builtin_amdgcn_mfma_f32_16x16x32_bf16(a0,b1,accS[0][1],0,0,0);
      accS[1][0]=__builtin_amdgcn_mfma_f32_16x16x32_bf16(a1,b0,accS[1][0],0,0,0);
      accS[1][1]=__builtin_amdgcn_mfma_f32_16x16x32_bf16(a1,b1,accS[1][1],0,0,0);
    }
    short* op=st+((size_t)((b*36+c)*6+h))*4096;
    #pragma unroll
    for(int mi=0;mi<2;mi++)
      #pragma unroll
      for(int ni=0;ni<2;ni++)
        #pragma unroll
        for(int r=0;r<4;r++){
          int p=wr*32+mi*16+4*kq+r, n=wc*32+ni*16+m16;
          op[p*64+n]=bf16rne(accS[mi][ni][r]);
        }
  }
  #pragma unroll
  for(int ti=0;ti<2;ti++){
    int t = ti? (7-wid) : wid;
    f32x4 accY[4];
    #pragma unroll
    for(int pi=0;pi<4;pi++) accY[pi]=(f32x4){0.f,0.f,0.f,0.f};
    int nslab=(t>>1)+1;
    for(int jt=0;jt<nslab;jt++){
      f32x4 accD[2];
      accD[0]=(f32x4){0.f,0.f,0.f,0.f}; accD[1]=(f32x4){0.f,0.f,0.f,0.f};
      #pragma unroll
      for(int ks=0;ks<2;ks++){
        short8 a =*(const short8*)&sC[t*16+m16][ks*32+kq*8];
        short8 b0=*(const short8*)&sB[jt*32+m16][ks*32+kq*8];
        short8 b1=*(const short8*)&sB[jt*32+16+m16][ks*32+kq*8];
        accD[0]=__builtin_amdgcn_mfma_f32_16x16x32_bf16(a,b0,accD[0],0,0,0);
        accD[1]=__builtin_amdgcn_mfma_f32_16x16x32_bf16(a,b1,accD[1],0,0,0);
      }
      int lrow=t*16+4*kq;
      #pragma unroll
      for(int sti=0;sti<2;sti++)
        #pragma unroll
        for(int r=0;r<4;r++){
          int l=lrow+r, s=jt*32+sti*16+m16;
          float v=(s<=l)? __expf(sAcs[l]-sAcs[s])*accD[sti][r] : 0.f;
          sM[l][sti*16+m16]=bf16u(v);
        }
      short8 am=*(const short8*)&sM[t*16+m16][kq*8];
      #pragma unroll
      for(int pi=0;pi<4;pi++){
        short8 bx=*(const short8*)&sXdT[pi*16+m16][jt*32+kq*8];
        accY[pi]=__builtin_amdgcn_mfma_f32_16x16x32_bf16(am,bx,accY[pi],0,0,0);
      }
    }
    #pragma unroll
    for(int pi=0;pi<4;pi++)
      #pragma unroll
      for(int r=0;r<4;r++){
        int l=t*16+4*kq+r, p=pi*16+m16;
        Y[(size_t)(base_row+l)*384+h*64+p]=bf16rne(accY[pi][r]);
      }
  }
}

// ---------------- sequential chunk scan (all 36 loads batched) ----------------
__global__ __launch_bounds__(256) void k_scan(const short* __restrict__ st, const float* __restrict__ csum,
                                              short* __restrict__ prevb){
  int bid=blockIdx.x;
  int seg=bid&15, bh=bid>>4;
  int b=bh/6, h=bh%6;
  __shared__ float sE[36];
  if(threadIdx.x<36) sE[threadIdx.x]=__expf(csum[(b*6+h)*36+threadIdx.x]);
  __syncthreads();
  int e=seg*256+threadIdx.x;
  size_t stride=(size_t)6*4096;
  size_t idx=((size_t)((b*36+0)*6+h))*4096+e;
  float v[36];
  #pragma unroll
  for(int j=0;j<36;j++) v[j]=b2fs(st[idx+j*stride]);   // 36 independent loads in flight
  float carry=0.f;
  #pragma unroll
  for(int j=0;j<36;j++){
    prevb[idx+j*stride]=bf16rne(carry);
    carry=carry*sE[j]+v[j];
  }
}

// ---------------- SSD part B (MFMA) ----------------
__global__ __launch_bounds__(256) void k_ssd_b(const short* __restrict__ xbc, const short* __restrict__ prevb,
    const float* __restrict__ acs, const float* __restrict__ Dv, short* __restrict__ Y){
  int bid=blockIdx.x;
  int h=bid%6, c=(bid/6)%36, b=bid/216;
  __shared__ unsigned short sC[128][68];
  __shared__ unsigned short sP[64][68];
  __shared__ float sAcs[128];
  int tid=threadIdx.x;
  int lane=tid&63, wid=tid>>6;
  int m16=lane&15, kq=lane>>4;
  int base_row=b*4608+c*128;
  const float* acsp=acs+((size_t)(b*6+h)*36+c)*128;
  if(tid<128) sAcs[tid]=acsp[tid];
  for(int i=tid;i<1024;i+=256){
    int l=i>>3, n0=(i&7)*8;
    short8 Cv=*(const short8*)(xbc+(size_t)(base_row+l)*512+448+n0);
    *(short8*)&sC[l][n0]=Cv;
  }
  const short* pp=prevb+((size_t)((b*36+c)*6+h))*4096;
  for(int i=tid;i<512;i+=256){
    int p_=i>>3, n0=(i&7)*8;
    short8 Pv=*(const short8*)(pp+p_*64+n0);
    *(short8*)&sP[p_][n0]=Pv;
  }
  __syncthreads();
  float Dh=Dv[h];
  int lt0=2*wid;
  f32x4 acc[2][4];
  #pragma unroll
  for(int li=0;li<2;li++)
    #pragma unroll
    for(int pi=0;pi<4;pi++) acc[li][pi]=(f32x4){0.f,0.f,0.f,0.f};
  #pragma unroll
  for(int ks=0;ks<2;ks++){
    short8 a0=*(const short8*)&sC[lt0*16+m16][ks*32+kq*8];
    short8 a1=*(const short8*)&sC[(lt0+1)*16+m16][ks*32+kq*8];
    #pragma unroll
    for(int pi=0;pi<4;pi++){
      short8 bp=*(const short8*)&sP[pi*16+m16][ks*32+kq*8];
      acc[0][pi]=__builtin_amdgcn_mfma_f32_16x16x32_bf16(a0,bp,acc[0][pi],0,0,0);
      acc[1][pi]=__builtin_amdgcn_mfma_f32_16x16x32_bf16(a1,bp,acc[1][pi],0,0,0);
    }
  }
  #pragma unroll
  for(int li=0;li<2;li++){
    #pragma unroll
    for(int r=0;r<4;r++){
      int l=(lt0+li)*16+4*kq+r;
      int row=base_row+l;
      float e=__expf(sAcs[l]);
      #pragma unroll
      for(int pi=0;pi<4;pi++){
        int p=pi*16+m16;
        size_t yi=(size_t)row*384+h*64+p;
        float xpv=b2fs(xbc[(size_t)row*512+h*64+p]);
        Y[yi]=bf16rne(b2fs(Y[yi])+acc[li][pi][r]*e+xpv*Dh);
      }
    }
  }
}

// ---------------- rmsgate (+ zero ECA partial) ----------------
__global__ __launch_bounds__(256) void k_rmsgate(const short* __restrict__ Y, const short* __restrict__ zx,
    const float* __restrict__ nw, short* __restrict__ yn, float* __restrict__ partial){
  if(blockIdx.x<3){
    int t=blockIdx.x*256+threadIdx.x;
    if(t<768) partial[t]=0.f;
  }
  int warp=threadIdx.x>>6, lane=threadIdx.x&63;
  int row=blockIdx.x*4+warp;
  float v[6]; float ss=0.f;
  #pragma unroll
  for(int j=0;j<6;j++){
    int cidx=lane+64*j;
    float y=b2fs(Y[(size_t)row*384+cidx]);
    float z=b2fs(zx[(size_t)row*904+cidx]);
    y*=siluf_(z);
    v[j]=y; ss+=y*y;
  }
  #pragma unroll
  for(int off=32;off;off>>=1) ss+=__shfl_xor(ss,off);
  float sc=rsqrtf(ss*(1.f/384.f)+1e-5f);
  #pragma unroll
  for(int j=0;j<6;j++){
    int cidx=lane+64*j;
    yn[(size_t)row*384+cidx]=bf16rne(v[j]*sc*nw[cidx]);
  }
}

// ---------------- windowed attention, split-K over 2 half-waves (128 thr/block) ----------------
__global__ __launch_bounds__(128) void k_att2(const short* __restrict__ qkv, const short* __restrict__ xn,
    const float* __restrict__ gw, const float* __restrict__ gb, short* __restrict__ obuf){
  int bid=blockIdx.x;
  int widx=bid/6, head=bid-widx*6;
  int b=widx/36, t=widx-b*36;
  int wi=t/6, wj=t-wi*6;
  int n=threadIdx.x&63, half=threadIdx.x>>6;
  __shared__ float sK[64][32], sV[64][32];
  __shared__ float sO2[64][32];
  __shared__ float sM2[64], sD2[64];
  const short* qp=qkv+(size_t)(widx*64+n)*576+head*32;
  float q[32];
  {
    short8 v0=*(const short8*)(qp),    v1=*(const short8*)(qp+8);
    short8 v2=*(const short8*)(qp+16), v3=*(const short8*)(qp+24);
    #pragma unroll
    for(int i=0;i<8;i++){ q[i]=b2fs(v0[i]); q[8+i]=b2fs(v1[i]); q[16+i]=b2fs(v2[i]); q[24+i]=b2fs(v3[i]); }
    short8 k0=*(const short8*)(qp+192+half*16), k1=*(const short8*)(qp+200+half*16);
    short8 u0=*(const short8*)(qp+384+half*16), u1=*(const short8*)(qp+392+half*16);
    #pragma unroll
    for(int i=0;i<8;i++){
      sK[n][half*16+i]=b2fs(k0[i]); sK[n][half*16+8+i]=b2fs(k1[i]);
      sV[n][half*16+i]=b2fs(u0[i]); sV[n][half*16+8+i]=b2fs(u1[i]);
    }
  }
  int h2=wi*8+(n>>3), w2=wj*8+(n&7);
  int rh=(h2<40)?0:((h2<44)?1:2);
  int rw=(w2<40)?0:((w2<44)?1:2);
  int myid=rh*3+rw;
  __syncthreads();
  const float scale=0.17677669529663687f;
  float p[32]; float mx=-1e30f;
  #pragma unroll 4
  for(int jj=0;jj<32;jj++){
    int j=half*32+jj;
    float sc=0;
    #pragma unroll
    for(int d=0;d<32;d++) sc+=q[d]*sK[j][d];
    int hj=wi*8+(j>>3), wjj=wj*8+(j&7);
    int rhj=(hj<40)?0:((hj<44)?1:2);
    int rwj=(wjj<40)?0:((wjj<44)?1:2);
    float m=((rhj*3+rwj)!=myid)? -100.f:0.f;
    float v=sc*scale+m;
    p[jj]=v; mx=fmaxf(mx,v);
  }
  float den=0;
  #pragma unroll
  for(int jj=0;jj<32;jj++){ p[jj]=__expf(p[jj]-mx); den+=p[jj]; }
  float o[32];
  #pragma unroll
  for(int d=0;d<32;d++) o[d]=0.f;
  #pragma unroll 4
  for(int jj=0;jj<32;jj++){
    float pj=p[jj];
    #pragma unroll
    for(int d=0;d<32;d++) o[d]+=pj*sV[half*32+jj][d];
  }
  if(half==1){
    sM2[n]=mx; sD2[n]=den;
    #pragma unroll
    for(int d=0;d<32;d++) sO2[n][d]=o[d];
  }
  __syncthreads();
  if(half==0){
    float m1=sM2[n], d1=sD2[n];
    float m=fmaxf(mx,m1);
    float e0=__expf(mx-m), e1=__expf(m1-m);
    float dent=den*e0+d1*e1;
    int xrow=map_row(widx*64+n,2);
    const short* xp=xn+(size_t)xrow*192;
    const float* gwp=gw+head*192;
    float g=0;
    #pragma unroll
    for(int c=0;c<24;c++){
      short8 xv=*(const short8*)(xp+c*8);
      float4 w0=*(const float4*)(gwp+c*8);
      float4 w1=*(const float4*)(gwp+c*8+4);
      g+=b2fs(xv[0])*w0.x+b2fs(xv[1])*w0.y+b2fs(xv[2])*w0.z+b2fs(xv[3])*w0.w
        +b2fs(xv[4])*w1.x+b2fs(xv[5])*w1.y+b2fs(xv[6])*w1.z+b2fs(xv[7])*w1.w;
    }
    g=sigmoidf_(g+gb[head]);
    float fac=g/dent;
    short* op=obuf+(size_t)(widx*64+n)*192+head*32;
    #pragma unroll
    for(int v8=0;v8<4;v8++){
      short8 w;
      #pragma unroll
      for(int j=0;j<8;j++){
        int d=v8*8+j;
        w[j]=bf16rne((o[d]*e0+sO2[n][d]*e1)*fac);
      }
      *(short8*)(op+v8*8)=w;
    }
  }
}

// ---------------- fused: xo = x + xf*ca(partial), then LayerNorm(xo) -> bf16 ----------------
__global__ __launch_bounds__(256) void k_xoln(const float* __restrict__ x, const float* __restrict__ xf,
    const float* __restrict__ partial, const float* __restrict__ ecaw,
    const float* __restrict__ w, const float* __restrict__ bvec,
    float* __restrict__ xo, short* __restrict__ out){
  int warp=threadIdx.x>>6, lane=threadIdx.x&63;
  int row=blockIdx.x*4+warp;
  int bidx=row/2304;
  const float* pp=partial+bidx*192;
  float e0=ecaw[0], e1=ecaw[1], e2=ecaw[2];
  auto cav=[&](int c)->float{
    float pv=pp[c];
    float lft=(c>0)?   pp[c-1]:0.f;
    float rgt=(c<191)? pp[c+1]:0.f;
    return sigmoidf_((e0*lft+e1*pv+e2*rgt)*(1.f/2304.f));
  };
  const float* xp=x+(size_t)row*192;
  const float* fp=xf+(size_t)row*192;
  float v0=xp[lane]    +fp[lane]    *cav(lane);
  float v1=xp[lane+64] +fp[lane+64] *cav(lane+64);
  float v2=xp[lane+128]+fp[lane+128]*cav(lane+128);
  float* op=xo+(size_t)row*192;
  op[lane]=v0; op[lane+64]=v1; op[lane+128]=v2;
  float s=v0+v1+v2, sq=v0*v0+v1*v1+v2*v2;
  #pragma unroll
  for(int off=32;off;off>>=1){ s+=__shfl_xor(s,off); sq+=__shfl_xor(sq,off); }
  float mean=s*(1.f/192.f), var=sq*(1.f/192.f)-mean*mean;
  float inv=rsqrtf(var+1e-5f);
  short* bp=out+(size_t)row*192;
  bp[lane]    =bf16rne((v0-mean)*inv*w[lane]    +bvec[lane]);
  bp[lane+64] =bf16rne((v1-mean)*inv*w[lane+64] +bvec[lane+64]);
  bp[lane+128]=bf16rne((v2-mean)*inv*w[lane+128]+bvec[lane+128]);
}

extern "C" void kernel_launch(void* const* d_in, const int* in_sizes, int n_in,
                              void* d_out, int out_size, void* d_ws, size_t ws_size,
                              hipStream_t stream){
  const float* x     =(const float*)d_in[0];
  const float* n1w   =(const float*)d_in[3];
  const float* n1b   =(const float*)d_in[4];
  const float* m_in_w=(const float*)d_in[5];
  const float* m_cw  =(const float*)d_in[6];
  const float* m_cb  =(const float*)d_in[7];
  const float* m_dtb =(const float*)d_in[8];
  const float* m_Al  =(const float*)d_in[9];
  const float* m_D   =(const float*)d_in[10];
  const float* m_nw  =(const float*)d_in[11];
  const float* m_ow  =(const float*)d_in[12];
  const float* qkvw  =(const float*)d_in[13];
  const float* qkvb  =(const float*)d_in[14];
  const float* projw =(const float*)d_in[15];
  const float* projb =(const float*)d_in[16];
  const float* gatew =(const float*)d_in[17];
  const float* gateb =(const float*)d_in[18];
  const float* fusw  =(const float*)d_in[19];
  const float* fusb  =(const float*)d_in[20];
  const float* ecaw  =(const float*)d_in[21];
  const float* n2w   =(const float*)d_in[22];
  const float* n2b   =(const float*)d_in[23];
  const float* fc1w  =(const float*)d_in[24];
  const float* fc1b  =(const float*)d_in[25];
  const float* fc2w  =(const float*)d_in[26];
  const float* fc2b  =(const float*)d_in[27];
  float* out=(float*)d_out;
  float* ws=(float*)d_ws;

  // arena (float offsets); bf16 buffers as short* aliases; zx stride = 904
  short* xn_bf  = (short*)(ws + 0);        //   884,736 fl [LN1 .. att2]
  short* wb     = (short*)(ws + 884736);   //   381,504 fl persistent
  short* zx_bf  = (short*)(ws + 1266240);  // 4,165,632 fl (9216x904) [in_proj .. rmsgate]
  short* xbc_bf = (short*)(ws + 5431872);  // 2,359,296 fl [conv .. ssd_b]
  float* dtb    = ws + 7791168;            //    55,296
  float* acs    = ws + 7846464;            //    55,296
  float* csum   = ws + 7901760;            //       512
  short* st_bf  = (short*)(ws + 7902272);  // 1,769,472 fl [ssd_a .. scan]
  short* prevb_bf=(short*)(ws + 9671744);  // 1,769,472 fl [scan .. ssd_b]
  short* Y_bf   = (short*)(ws + 11441216); // region 3,538,944 fl [ssd_a .. rmsgate]
  float* bigbf  = ws + 14980160;           // 3,538,944   (yn | h1 bf16)
  short* qkv_bf = (short*)(ws + 18519104); // 2,654,208 fl [inqkv .. att2]
  short* obuf_bf= (short*)(ws + 21173312); //   884,736 fl [att2 .. proj]
  // aliases (disjoint lifetimes)
  short* hbuf_bf= xn_bf;                   // [xoln .. fc1]
  short* xcat_bf= prevb_bf;                // [out_proj .. fusion]
  float* xf     = (float*)st_bf;           // [fusion .. xoln]
  float* xo     = (float*)Y_bf;            // [xoln .. fc2]
  short* yn_bf  = (short*)bigbf;           // [rmsgate .. out_proj]
  short* h1_bf  = (short*)bigbf;           // [fc1 .. fc2]
  float* partial= dtb;                     // ECA sums [rmsgate .. xoln]
  // bf16 weight segments
  short* wb_in  = wb + 0;
  short* wb_qkv = wb + 173184;
  short* wb_out = wb + 283776;
  short* wb_proj= wb + 357504;
  short* wb_fus = wb + 394368;
  short* wb_fc1 = wb + 468096;
  short* wb_fc2 = wb + 615552;

  // 1. LN1 + weight convert
  k_lnw2b<<<7043,256,0,stream>>>(x,n1w,n1b,xn_bf, m_in_w,qkvw,m_ow,projw,fusw,fc1w,fc2w,wb);
  // 2. in_proj + qkv
  k_gemm_inqkv<<<dim3(144,24),256,0,stream>>>(xn_bf,wb_in,zx_bf,wb_qkv,qkvb,qkv_bf);
  // 3. attention (qkv L2-hot; own obuf region)
  k_att2<<<864,128,0,stream>>>(qkv_bf,xn_bf,gatew,gateb,obuf_bf);
  // 4. conv + prep
  k_convprep<<<2736,256,0,stream>>>(zx_bf,m_cw,m_cb,xbc_bf, m_dtb,m_Al,dtb,acs,csum);
  // 5. SSD part A
  k_ssd_a<<<432,256,0,stream>>>(xbc_bf,dtb,acs,csum,st_bf,Y_bf);
  // 6. chunk scan
  k_scan<<<192,256,0,stream>>>(st_bf,csum,prevb_bf);
  // 7. SSD part B
  k_ssd_b<<<432,256,0,stream>>>(xbc_bf,prevb_bf,acs,m_D,Y_bf);
  // 8. gated RMS norm (+ zero partial)
  k_rmsgate<<<2304,256,0,stream>>>(Y_bf,zx_bf,m_nw,yn_bf,partial);
  // 9. mamba out_proj -> xcat[:,0:192]
  k_gemm<384><<<dim3(144,3),256,0,stream>>>(yn_bf,wb_out,nullptr,nullptr,nullptr,xcat_bf, 192,384,0, 0,1,0, nullptr);
  // 10. attn proj -> xcat[:,192:384]
  k_gemm<192><<<dim3(144,3),256,0,stream>>>(obuf_bf,wb_proj,projb,nullptr,nullptr,xcat_bf, 192,384,192, 0,2,0, nullptr);
  // 11. fusion -> xf fp32 + ECA pooling
  k_gemm<384><<<dim3(144,3),256,0,stream>>>(xcat_bf,wb_fus,fusb,nullptr,xf,nullptr, 192,192,0, 0,0,0, partial);
  // 12. fused xo + ECA sigmoid + LN2
  k_xoln<<<2304,256,0,stream>>>(x,xf,partial,ecaw,n2w,n2b,xo,hbuf_bf);
  // 13. fc1 + gelu
  k_gemm<192><<<dim3(144,12),256,0,stream>>>(hbuf_bf,wb_fc1,fc1b,nullptr,nullptr,h1_bf, 768,768,0, 0,0,2, nullptr);
  // 14. fc2 + residual -> out
  k_gemm<768><<<dim3(144,3),256,0,stream>>>(h1_bf,wb_fc2,fc2b,xo,out,nullptr, 192,192,0, 0,0,3, nullptr);
}

// Round 19
// 162.525 us; speedup vs baseline: 1.0605x; 1.0410x over previous
//
#include <hip/hip_runtime.h>
#include <math.h>

#define DEV __device__ __forceinline__

typedef __attribute__((ext_vector_type(8))) short short8;
typedef __attribute__((ext_vector_type(4))) float f32x4;

DEV float sigmoidf_(float x){ return 1.f/(1.f+__expf(-x)); }
DEV float siluf_(float x){ return x/(1.f+__expf(-x)); }
DEV float softplusf_(float x){ return (x>20.f)? x : log1pf(__expf(x)); }

DEV short bf16rne(float f){
  unsigned u=__float_as_uint(f);
  unsigned r=(u + 0x7FFFu + ((u>>16)&1u))>>16;
  return (short)r;
}
DEV unsigned short bf16u(float f){ return (unsigned short)bf16rne(f); }
DEV float b2f(unsigned short u){ return __uint_as_float(((unsigned)u)<<16); }
DEV float b2fs(short u){ return __uint_as_float(((unsigned)(unsigned short)u)<<16); }

// async global->LDS, 16B per lane
DEV void gll16(const void* g, void* l){
  __builtin_amdgcn_global_load_lds(
      (const __attribute__((address_space(1))) void*)g,
      (__attribute__((address_space(3))) void*)(unsigned)(uintptr_t)l,
      16, 0, 0);
}

// row remap: 0 identity; 1 mamba interleave; 2 shifted-window gather
DEV int map_row(int r, int mode){
  if(mode==1){
    int b=r/4608; int gl=r-b*4608;
    return ((gl&1)*2+b)*2304 + (gl>>1);
  }
  if(mode==2){
    int widx=r>>6, n=r&63;
    int b=widx/36, t=widx-b*36;
    int wi=t/6, wj=t-wi*6;
    int h2=wi*8+(n>>3), w2=wj*8+(n&7);
    int ho=h2+4; if(ho>=48) ho-=48;
    int wo=w2+4; if(wo>=48) wo-=48;
    return b*2304 + ho*48 + wo;
  }
  return r;
}

// ================= unified double-buffered bf16 MFMA GEMM body (static 32KB LDS) =================
template<int K>
DEV void gemm_body(const short* __restrict__ A, const short* __restrict__ W,
    const float* __restrict__ bias, const float* __restrict__ res,
    float* __restrict__ Of, short* __restrict__ Ob,
    int N, int ldo, int col_off, int gmode, int smode, int epi,
    int bx, int by, float* __restrict__ pool){
  constexpr int NP=K/64;
  __shared__ short sMem[16384];                    // 32 KB
  short (*sA)[64][64]=(short(*)[64][64])sMem;
  short (*sB)[64][64]=(short(*)[64][64])(sMem+8192);
  float* sO=(float*)sMem;
  int tid=threadIdx.x, lane=tid&63, wid=tid>>6;
  int m16=lane&15, kq=lane>>4;
  int bm=bx*64, bn=by*64;
  int lrow=lane>>3;
  int lcol=((lane&7)^lrow)<<3;
  int sx=(m16&7)<<3;
  const short* ap[2]; const short* wp[2];
  #pragma unroll
  for(int t=0;t<2;t++){
    int i8=wid+t*4;
    int arow=map_row(bm+i8*8+lrow,gmode);
    ap[t]=A+(size_t)arow*K+lcol;
    int n=bn+i8*8+lrow;
    if(n>=N) n=N-1;                                // clamp: finite garbage, masked at store
    wp[t]=W+(size_t)n*K+lcol;
  }
  f32x4 acc[4];
  #pragma unroll
  for(int ni=0;ni<4;ni++) acc[ni]=(f32x4){0.f,0.f,0.f,0.f};

  auto stage=[&](int p,int b){
    #pragma unroll
    for(int t=0;t<2;t++){
      int i8=wid+t*4;
      gll16(ap[t]+p*64, &sA[b][i8*8][0]);
      gll16(wp[t]+p*64, &sB[b][i8*8][0]);
    }
  };
  auto compute=[&](int p,int b){
    __builtin_amdgcn_s_setprio(1);
    #pragma unroll
    for(int half=0;half<2;half++){
      int k2=(half*32 + kq*8) ^ sx;
      short8 af=*(const short8*)&sA[b][wid*16+m16][k2];
      #pragma unroll
      for(int ni=0;ni<4;ni++){
        short8 bf=*(const short8*)&sB[b][ni*16+m16][k2];
        acc[ni]=__builtin_amdgcn_mfma_f32_16x16x32_bf16(af,bf,acc[ni],0,0,0);
      }
    }
    __builtin_amdgcn_s_setprio(0);
  };

  stage(0,0);
  if(NP>1) stage(1,1);
  #pragma unroll
  for(int p=0;p<NP;p++){
    if(p+1<NP) asm volatile("s_waitcnt vmcnt(4)":::"memory");
    else       asm volatile("s_waitcnt vmcnt(0)":::"memory");
    __builtin_amdgcn_s_barrier();
    compute(p,p&1);
    if(p+2<NP){
      __builtin_amdgcn_s_barrier();
      stage(p+2,p&1);
    }
  }

  __syncthreads();
  {
    int mbase=wid*16+4*kq;
    #pragma unroll
    for(int ni=0;ni<4;ni++)
      #pragma unroll
      for(int r=0;r<4;r++)
        sO[(mbase+r)*65 + ni*16+m16]=acc[ni][r];
  }
  __syncthreads();
  int erow=tid>>3, c0=(tid&7)*8;
  #pragma unroll
  for(int rd=0;rd<2;rd++){
    int ml=rd*32+erow;
    int m=bm+ml;
    int orow=map_row(m,smode);
    float v[8];
    #pragma unroll
    for(int j=0;j<8;j++) v[j]=sO[ml*65+c0+j];
    const float* rp=res? res+(size_t)orow*ldo+col_off : nullptr;
    #pragma unroll
    for(int j=0;j<8;j++){
      int nn=bn+c0+j;
      float val=v[j];
      if(bias && nn<N) val+=bias[nn];
      if(epi==2) val=0.5f*val*(1.f+erff(val*0.70710678118654752f));
      else if(epi==3) val+=rp[nn];
      v[j]=val;
    }
    size_t obase=(size_t)orow*ldo+col_off+bn+c0;
    if(bn+c0+7<N){
      if(Ob){
        short8 w;
        #pragma unroll
        for(int j=0;j<8;j++) w[j]=bf16rne(v[j]);
        *(short8*)(Ob+obase)=w;
      } else {
        float4 f0={v[0],v[1],v[2],v[3]}, f1={v[4],v[5],v[6],v[7]};
        *(float4*)(Of+obase)=f0;
        *(float4*)(Of+obase+4)=f1;
      }
    } else {
      #pragma unroll
      for(int j=0;j<8;j++){
        int nn=bn+c0+j;
        if(nn<N){ if(Ob) Ob[obase+j]=bf16rne(v[j]); else Of[obase+j]=v[j]; }
      }
    }
  }
  if(pool){
    if(tid<64){
      float s=0;
      #pragma unroll 8
      for(int ml=0;ml<64;ml++) s+=sO[ml*65+tid];
      if(bias) s+=64.f*bias[bn+tid];
      atomicAdd(&pool[(bm/2304)*192 + bn+tid], s);
    }
  }
}

template<int K>
__global__ __launch_bounds__(256,4) void k_gemm(const short* __restrict__ A, const short* __restrict__ W,
    const float* __restrict__ bias, const float* __restrict__ res,
    float* __restrict__ Of, short* __restrict__ Ob,
    int N, int ldo, int col_off, int gmode, int smode, int epi, float* __restrict__ pool){
  gemm_body<K>(A,W,bias,res,Of,Ob,N,ldo,col_off,gmode,smode,epi,blockIdx.x,blockIdx.y,pool);
}

// merged in_proj + qkv: single call site -> single 32KB LDS
__global__ __launch_bounds__(256,4) void k_gemm_inqkv(const short* __restrict__ xn,
    const short* __restrict__ w_in, short* __restrict__ zx,
    const short* __restrict__ w_qkv, const float* __restrict__ qkvb, short* __restrict__ qkv){
  int by=blockIdx.y;
  const short* W; short* O; const float* bias; int N,ldo,gm,byy;
  if(by<15){ W=w_in;  O=zx;  bias=nullptr; N=902; ldo=904; gm=1; byy=by; }
  else     { W=w_qkv; O=qkv; bias=qkvb;    N=576; ldo=576; gm=2; byy=by-15; }
  gemm_body<192>(xn,W,bias,nullptr,nullptr,O, N,ldo,0, gm,0,0, blockIdx.x,byy, nullptr);
}

// ---------------- merged LayerNorm1 + weight bf16 pre-convert ----------------
__global__ __launch_bounds__(256) void k_lnw2b(const float* __restrict__ in, const float* __restrict__ w,
    const float* __restrict__ b, short* __restrict__ out,
    const float* __restrict__ w0,const float* __restrict__ w1,const float* __restrict__ w2,
    const float* __restrict__ w3,const float* __restrict__ w4,const float* __restrict__ w5,
    const float* __restrict__ w6, short* __restrict__ dst){
  int bid=blockIdx.x;
  if(bid<2304){
    int warp=threadIdx.x>>6, lane=threadIdx.x&63;
    int row=bid*4+warp;
    const float* ip=in+(size_t)row*192;
    float v0=ip[lane], v1=ip[lane+64], v2=ip[lane+128];
    float s=v0+v1+v2, sq=v0*v0+v1*v1+v2*v2;
    #pragma unroll
    for(int off=32;off;off>>=1){ s+=__shfl_xor(s,off); sq+=__shfl_xor(sq,off); }
    float mean=s*(1.f/192.f), var=sq*(1.f/192.f)-mean*mean;
    float inv=rsqrtf(var+1e-5f);
    short* op=out+(size_t)row*192;
    op[lane]    =bf16rne((v0-mean)*inv*w[lane]    +b[lane]);
    op[lane+64] =bf16rne((v1-mean)*inv*w[lane+64] +b[lane+64]);
    op[lane+128]=bf16rne((v2-mean)*inv*w[lane+128]+b[lane+128]);
  } else {
    int flat=bid-2304;
    int seg=flat/677;
    int i=(flat-seg*677)*256+threadIdx.x;
    const float* src; int size, off;
    switch(seg){
      case 0: src=w0; size=173184; off=0;      break;
      case 1: src=w1; size=110592; off=173184; break;
      case 2: src=w2; size=73728;  off=283776; break;
      case 3: src=w3; size=36864;  off=357504; break;
      case 4: src=w4; size=73728;  off=394368; break;
      case 5: src=w5; size=147456; off=468096; break;
      default:src=w6; size=147456; off=615552; break;
    }
    if(i<size) dst[off+i]=bf16rne(src[i]);
  }
}

// ---------------- merged conv + prep ----------------
__global__ __launch_bounds__(256) void k_convprep(const short* __restrict__ zx, const float* __restrict__ cw,
    const float* __restrict__ cb, short* __restrict__ xbc,
    const float* __restrict__ dt_bias, const float* __restrict__ A_log,
    float* __restrict__ dtb, float* __restrict__ acs, float* __restrict__ csum){
  int bid=blockIdx.x;
  if(bid<2304){
    int idx=bid*256+threadIdx.x;
    int ch0=(idx&63)*8; int rl=idx>>6;
    int l=rl%4608;
    const short* base=zx+(size_t)rl*904+384+ch0;
    short8 x0=*(const short8*)(base);
    short8 x1={0,0,0,0,0,0,0,0},x2=x1,x3=x1;
    if(l>=1) x1=*(const short8*)(base-904);
    if(l>=2) x2=*(const short8*)(base-2*904);
    if(l>=3) x3=*(const short8*)(base-3*904);
    short8 out;
    #pragma unroll
    for(int j=0;j<8;j++){
      float4 w=*(const float4*)(cw+(ch0+j)*4);
      float acc=cb[ch0+j]
        + b2fs(x3[j])*w.x + b2fs(x2[j])*w.y + b2fs(x1[j])*w.z + b2fs(x0[j])*w.w;
      out[j]=bf16rne(siluf_(acc));
    }
    *(short8*)(xbc+(size_t)rl*512+ch0)=out;
  } else {
    int pb=bid-2304;
    int c=pb%36, h=(pb/36)%6, b=pb/216;
    int l=threadIdx.x;
    __shared__ float sb[128];
    if(l<128){
      int row=b*4608+c*128+l;
      float xv=b2fs(zx[(size_t)row*904+896+h])+dt_bias[h];
      float dt=softplusf_(xv);
      dtb[row*6+h]=dt;
      sb[l]=-__expf(A_log[h])*dt;
    }
    __syncthreads();
    for(int off=1;off<128;off<<=1){
      float add=(l>=off && l<128)? sb[l-off]:0.f;
      __syncthreads();
      if(l<128) sb[l]+=add;
      __syncthreads();
    }
    if(l<128){
      acs[((size_t)(b*6+h)*36+c)*128+l]=sb[l];
      if(l==127) csum[(b*6+h)*36+c]=sb[127];
    }
  }
}

// ---------------- fused SSD part A (MFMA): states + diagonal Y (bf16 Y) ----------------
__global__ __launch_bounds__(256) void k_ssd_a(const short* __restrict__ xbc, const float* __restrict__ dtb,
    const float* __restrict__ acs, const float* __restrict__ csum,
    short* __restrict__ st, short* __restrict__ Y){
  int bid=blockIdx.x;
  int h=bid%6, c=(bid/6)%36, b=bid/216;
  __shared__ unsigned short sB[128][68];
  __shared__ unsigned short sC[128][68];
  __shared__ unsigned short sXdT[64][132];
  __shared__ unsigned short sBTE[64][132];
  __shared__ unsigned short sM[128][36];
  __shared__ float sAcs[128];
  __shared__ float sE[128];
  int tid=threadIdx.x;
  int lane=tid&63, wid=tid>>6;
  int m16=lane&15, kq=lane>>4;
  int base_row=b*4608+c*128;
  const float* acsp=acs+((size_t)(b*6+h)*36+c)*128;
  float tot=csum[(b*6+h)*36+c];
  if(tid<128){ float a=acsp[tid]; sAcs[tid]=a; sE[tid]=__expf(tot-a); }
  __syncthreads();
  for(int i=tid;i<1024;i+=256){
    int l=i>>3, n0=(i&7)*8;
    int row=base_row+l;
    const short* rp=xbc+(size_t)row*512;
    short8 Bv=*(const short8*)(rp+384+n0);
    short8 Cv=*(const short8*)(rp+448+n0);
    short8 Xv=*(const short8*)(rp+h*64+n0);
    float dt=dtb[row*6+h];
    float e=sE[l];
    *(short8*)&sB[l][n0]=Bv;
    *(short8*)&sC[l][n0]=Cv;
    #pragma unroll
    for(int j=0;j<8;j++){
      sXdT[n0+j][l]=bf16u(b2fs(Xv[j])*dt);
      sBTE[n0+j][l]=bf16u(b2fs(Bv[j])*e);
    }
  }
  __syncthreads();
  {
    int wr=wid>>1, wc=wid&1;
    f32x4 accS[2][2];
    #pragma unroll
    for(int mi=0;mi<2;mi++)
      #pragma unroll
      for(int ni=0;ni<2;ni++) accS[mi][ni]=(f32x4){0.f,0.f,0.f,0.f};
    #pragma unroll
    for(int ks=0;ks<4;ks++){
      short8 a0=*(const short8*)&sXdT[wr*32+m16][ks*32+kq*8];
      short8 a1=*(const short8*)&sXdT[wr*32+16+m16][ks*32+kq*8];
      short8 b0=*(const short8*)&sBTE[wc*32+m16][ks*32+kq*8];
      short8 b1=*(const short8*)&sBTE[wc*32+16+m16][ks*32+kq*8];
      accS[0][0]=__builtin_amdgcn_mfma_f32_16x16x32_bf16(a0,b0,accS[0][0],0,0,0);
      accS[0][1]=__builtin_amdgcn_mfma_f32_16x16x32_bf16(a0,b1,accS[0][1],0,0,0);
      accS[1][0]=__builtin_amdgcn_mfma_f32_16x16x32_bf16(a1,b0,accS[1][0],0,0,0);
      accS[1][1]=__builtin_amdgcn_mfma_f32_16x16x32_bf16(a1,b1,accS[1][1],0,0,0);
    }
    short* op=st+((size_t)((b*36+c)*6+h))*4096;
    #pragma unroll
    for(int mi=0;mi<2;mi++)
      #pragma unroll
      for(int ni=0;ni<2;ni++)
        #pragma unroll
        for(int r=0;r<4;r++){
          int p=wr*32+mi*16+4*kq+r, n=wc*32+ni*16+m16;
          op[p*64+n]=bf16rne(accS[mi][ni][r]);
        }
  }
  #pragma unroll
  for(int ti=0;ti<2;ti++){
    int t = ti? (7-wid) : wid;
    f32x4 accY[4];
    #pragma unroll
    for(int pi=0;pi<4;pi++) accY[pi]=(f32x4){0.f,0.f,0.f,0.f};
    int nslab=(t>>1)+1;
    for(int jt=0;jt<nslab;jt++){
      f32x4 accD[2];
      accD[0]=(f32x4){0.f,0.f,0.f,0.f}; accD[1]=(f32x4){0.f,0.f,0.f,0.f};
      #pragma unroll
      for(int ks=0;ks<2;ks++){
        short8 a =*(const short8*)&sC[t*16+m16][ks*32+kq*8];
        short8 b0=*(const short8*)&sB[jt*32+m16][ks*32+kq*8];
        short8 b1=*(const short8*)&sB[jt*32+16+m16][ks*32+kq*8];
        accD[0]=__builtin_amdgcn_mfma_f32_16x16x32_bf16(a,b0,accD[0],0,0,0);
        accD[1]=__builtin_amdgcn_mfma_f32_16x16x32_bf16(a,b1,accD[1],0,0,0);
      }
      int lrow=t*16+4*kq;
      #pragma unroll
      for(int sti=0;sti<2;sti++)
        #pragma unroll
        for(int r=0;r<4;r++){
          int l=lrow+r, s=jt*32+sti*16+m16;
          float v=(s<=l)? __expf(sAcs[l]-sAcs[s])*accD[sti][r] : 0.f;
          sM[l][sti*16+m16]=bf16u(v);
        }
      short8 am=*(const short8*)&sM[t*16+m16][kq*8];
      #pragma unroll
      for(int pi=0;pi<4;pi++){
        short8 bx=*(const short8*)&sXdT[pi*16+m16][jt*32+kq*8];
        accY[pi]=__builtin_amdgcn_mfma_f32_16x16x32_bf16(am,bx,accY[pi],0,0,0);
      }
    }
    #pragma unroll
    for(int pi=0;pi<4;pi++)
      #pragma unroll
      for(int r=0;r<4;r++){
        int l=t*16+4*kq+r, p=pi*16+m16;
        Y[(size_t)(base_row+l)*384+h*64+p]=bf16rne(accY[pi][r]);
      }
  }
}

// ---------------- sequential chunk scan (4-deep load batching) ----------------
__global__ __launch_bounds__(256) void k_scan(const short* __restrict__ st, const float* __restrict__ csum,
                                              short* __restrict__ prevb){
  int bid=blockIdx.x;
  int seg=bid&15, bh=bid>>4;
  int b=bh/6, h=bh%6;
  __shared__ float sE[36];
  if(threadIdx.x<36) sE[threadIdx.x]=__expf(csum[(b*6+h)*36+threadIdx.x]);
  __syncthreads();
  int e=seg*256+threadIdx.x;
  size_t stride=(size_t)6*4096;
  size_t idx=((size_t)((b*36+0)*6+h))*4096+e;
  float carry=0.f;
  for(int c4=0;c4<36;c4+=4){
    float v[4];
    #pragma unroll
    for(int j=0;j<4;j++) v[j]=b2fs(st[idx+j*stride]);
    #pragma unroll
    for(int j=0;j<4;j++){
      prevb[idx+j*stride]=bf16rne(carry);
      carry=carry*sE[c4+j]+v[j];
    }
    idx+=4*stride;
  }
}

// ---------------- SSD part B (MFMA) ----------------
__global__ __launch_bounds__(256) void k_ssd_b(const short* __restrict__ xbc, const short* __restrict__ prevb,
    const float* __restrict__ acs, const float* __restrict__ Dv, short* __restrict__ Y){
  int bid=blockIdx.x;
  int h=bid%6, c=(bid/6)%36, b=bid/216;
  __shared__ unsigned short sC[128][68];
  __shared__ unsigned short sP[64][68];
  __shared__ float sAcs[128];
  int tid=threadIdx.x;
  int lane=tid&63, wid=tid>>6;
  int m16=lane&15, kq=lane>>4;
  int base_row=b*4608+c*128;
  const float* acsp=acs+((size_t)(b*6+h)*36+c)*128;
  if(tid<128) sAcs[tid]=acsp[tid];
  for(int i=tid;i<1024;i+=256){
    int l=i>>3, n0=(i&7)*8;
    short8 Cv=*(const short8*)(xbc+(size_t)(base_row+l)*512+448+n0);
    *(short8*)&sC[l][n0]=Cv;
  }
  const short* pp=prevb+((size_t)((b*36+c)*6+h))*4096;
  for(int i=tid;i<512;i+=256){
    int p_=i>>3, n0=(i&7)*8;
    short8 Pv=*(const short8*)(pp+p_*64+n0);
    *(short8*)&sP[p_][n0]=Pv;
  }
  __syncthreads();
  float Dh=Dv[h];
  int lt0=2*wid;
  f32x4 acc[2][4];
  #pragma unroll
  for(int li=0;li<2;li++)
    #pragma unroll
    for(int pi=0;pi<4;pi++) acc[li][pi]=(f32x4){0.f,0.f,0.f,0.f};
  #pragma unroll
  for(int ks=0;ks<2;ks++){
    short8 a0=*(const short8*)&sC[lt0*16+m16][ks*32+kq*8];
    short8 a1=*(const short8*)&sC[(lt0+1)*16+m16][ks*32+kq*8];
    #pragma unroll
    for(int pi=0;pi<4;pi++){
      short8 bp=*(const short8*)&sP[pi*16+m16][ks*32+kq*8];
      acc[0][pi]=__builtin_amdgcn_mfma_f32_16x16x32_bf16(a0,bp,acc[0][pi],0,0,0);
      acc[1][pi]=__builtin_amdgcn_mfma_f32_16x16x32_bf16(a1,bp,acc[1][pi],0,0,0);
    }
  }
  #pragma unroll
  for(int li=0;li<2;li++){
    #pragma unroll
    for(int r=0;r<4;r++){
      int l=(lt0+li)*16+4*kq+r;
      int row=base_row+l;
      float e=__expf(sAcs[l]);
      #pragma unroll
      for(int pi=0;pi<4;pi++){
        int p=pi*16+m16;
        size_t yi=(size_t)row*384+h*64+p;
        float xpv=b2fs(xbc[(size_t)row*512+h*64+p]);
        Y[yi]=bf16rne(b2fs(Y[yi])+acc[li][pi][r]*e+xpv*Dh);
      }
    }
  }
}

// ---------------- rmsgate (+ zero ECA partial) ----------------
__global__ __launch_bounds__(256) void k_rmsgate(const short* __restrict__ Y, const short* __restrict__ zx,
    const float* __restrict__ nw, short* __restrict__ yn, float* __restrict__ partial){
  if(blockIdx.x<3){
    int t=blockIdx.x*256+threadIdx.x;
    if(t<768) partial[t]=0.f;
  }
  int warp=threadIdx.x>>6, lane=threadIdx.x&63;
  int row=blockIdx.x*4+warp;
  float v[6]; float ss=0.f;
  #pragma unroll
  for(int j=0;j<6;j++){
    int cidx=lane+64*j;
    float y=b2fs(Y[(size_t)row*384+cidx]);
    float z=b2fs(zx[(size_t)row*904+cidx]);
    y*=siluf_(z);
    v[j]=y; ss+=y*y;
  }
  #pragma unroll
  for(int off=32;off;off>>=1) ss+=__shfl_xor(ss,off);
  float sc=rsqrtf(ss*(1.f/384.f)+1e-5f);
  #pragma unroll
  for(int j=0;j<6;j++){
    int cidx=lane+64*j;
    yn[(size_t)row*384+cidx]=bf16rne(v[j]*sc*nw[cidx]);
  }
}

// ---------------- windowed attention, split-K over 2 half-waves (128 thr/block) ----------------
__global__ __launch_bounds__(128) void k_att2(const short* __restrict__ qkv, const short* __restrict__ xn,
    const float* __restrict__ gw, const float* __restrict__ gb, short* __restrict__ obuf){
  int bid=blockIdx.x;
  int widx=bid/6, head=bid-widx*6;
  int b=widx/36, t=widx-b*36;
  int wi=t/6, wj=t-wi*6;
  int n=threadIdx.x&63, half=threadIdx.x>>6;
  __shared__ float sK[64][32], sV[64][32];
  __shared__ float sO2[64][32];
  __shared__ float sM2[64], sD2[64];
  const short* qp=qkv+(size_t)(widx*64+n)*576+head*32;
  float q[32];
  {
    short8 v0=*(const short8*)(qp),    v1=*(const short8*)(qp+8);
    short8 v2=*(const short8*)(qp+16), v3=*(const short8*)(qp+24);
    #pragma unroll
    for(int i=0;i<8;i++){ q[i]=b2fs(v0[i]); q[8+i]=b2fs(v1[i]); q[16+i]=b2fs(v2[i]); q[24+i]=b2fs(v3[i]); }
    short8 k0=*(const short8*)(qp+192+half*16), k1=*(const short8*)(qp+200+half*16);
    short8 u0=*(const short8*)(qp+384+half*16), u1=*(const short8*)(qp+392+half*16);
    #pragma unroll
    for(int i=0;i<8;i++){
      sK[n][half*16+i]=b2fs(k0[i]); sK[n][half*16+8+i]=b2fs(k1[i]);
      sV[n][half*16+i]=b2fs(u0[i]); sV[n][half*16+8+i]=b2fs(u1[i]);
    }
  }
  int h2=wi*8+(n>>3), w2=wj*8+(n&7);
  int rh=(h2<40)?0:((h2<44)?1:2);
  int rw=(w2<40)?0:((w2<44)?1:2);
  int myid=rh*3+rw;
  __syncthreads();
  const float scale=0.17677669529663687f;
  float p[32]; float mx=-1e30f;
  #pragma unroll 4
  for(int jj=0;jj<32;jj++){
    int j=half*32+jj;
    float sc=0;
    #pragma unroll
    for(int d=0;d<32;d++) sc+=q[d]*sK[j][d];
    int hj=wi*8+(j>>3), wjj=wj*8+(j&7);
    int rhj=(hj<40)?0:((hj<44)?1:2);
    int rwj=(wjj<40)?0:((wjj<44)?1:2);
    float m=((rhj*3+rwj)!=myid)? -100.f:0.f;
    float v=sc*scale+m;
    p[jj]=v; mx=fmaxf(mx,v);
  }
  float den=0;
  #pragma unroll
  for(int jj=0;jj<32;jj++){ p[jj]=__expf(p[jj]-mx); den+=p[jj]; }
  float o[32];
  #pragma unroll
  for(int d=0;d<32;d++) o[d]=0.f;
  #pragma unroll 4
  for(int jj=0;jj<32;jj++){
    float pj=p[jj];
    #pragma unroll
    for(int d=0;d<32;d++) o[d]+=pj*sV[half*32+jj][d];
  }
  if(half==1){
    sM2[n]=mx; sD2[n]=den;
    #pragma unroll
    for(int d=0;d<32;d++) sO2[n][d]=o[d];
  }
  __syncthreads();
  if(half==0){
    float m1=sM2[n], d1=sD2[n];
    float m=fmaxf(mx,m1);
    float e0=__expf(mx-m), e1=__expf(m1-m);
    float dent=den*e0+d1*e1;
    int xrow=map_row(widx*64+n,2);
    const short* xp=xn+(size_t)xrow*192;
    const float* gwp=gw+head*192;
    float g=0;
    #pragma unroll
    for(int c=0;c<24;c++){
      short8 xv=*(const short8*)(xp+c*8);
      float4 w0=*(const float4*)(gwp+c*8);
      float4 w1=*(const float4*)(gwp+c*8+4);
      g+=b2fs(xv[0])*w0.x+b2fs(xv[1])*w0.y+b2fs(xv[2])*w0.z+b2fs(xv[3])*w0.w
        +b2fs(xv[4])*w1.x+b2fs(xv[5])*w1.y+b2fs(xv[6])*w1.z+b2fs(xv[7])*w1.w;
    }
    g=sigmoidf_(g+gb[head]);
    float fac=g/dent;
    short* op=obuf+(size_t)(widx*64+n)*192+head*32;
    #pragma unroll
    for(int v8=0;v8<4;v8++){
      short8 w;
      #pragma unroll
      for(int j=0;j<8;j++){
        int d=v8*8+j;
        w[j]=bf16rne((o[d]*e0+sO2[n][d]*e1)*fac);
      }
      *(short8*)(op+v8*8)=w;
    }
  }
}

// ---------------- fused: xo = x + xf*ca(partial), then LayerNorm(xo) -> bf16 ----------------
__global__ __launch_bounds__(256) void k_xoln(const float* __restrict__ x, const float* __restrict__ xf,
    const float* __restrict__ partial, const float* __restrict__ ecaw,
    const float* __restrict__ w, const float* __restrict__ bvec,
    float* __restrict__ xo, short* __restrict__ out){
  int warp=threadIdx.x>>6, lane=threadIdx.x&63;
  int row=blockIdx.x*4+warp;
  int bidx=row/2304;
  const float* pp=partial+bidx*192;
  float e0=ecaw[0], e1=ecaw[1], e2=ecaw[2];
  auto cav=[&](int c)->float{
    float pv=pp[c];
    float lft=(c>0)?   pp[c-1]:0.f;
    float rgt=(c<191)? pp[c+1]:0.f;
    return sigmoidf_((e0*lft+e1*pv+e2*rgt)*(1.f/2304.f));
  };
  const float* xp=x+(size_t)row*192;
  const float* fp=xf+(size_t)row*192;
  float v0=xp[lane]    +fp[lane]    *cav(lane);
  float v1=xp[lane+64] +fp[lane+64] *cav(lane+64);
  float v2=xp[lane+128]+fp[lane+128]*cav(lane+128);
  float* op=xo+(size_t)row*192;
  op[lane]=v0; op[lane+64]=v1; op[lane+128]=v2;
  float s=v0+v1+v2, sq=v0*v0+v1*v1+v2*v2;
  #pragma unroll
  for(int off=32;off;off>>=1){ s+=__shfl_xor(s,off); sq+=__shfl_xor(sq,off); }
  float mean=s*(1.f/192.f), var=sq*(1.f/192.f)-mean*mean;
  float inv=rsqrtf(var+1e-5f);
  short* bp=out+(size_t)row*192;
  bp[lane]    =bf16rne((v0-mean)*inv*w[lane]    +bvec[lane]);
  bp[lane+64] =bf16rne((v1-mean)*inv*w[lane+64] +bvec[lane+64]);
  bp[lane+128]=bf16rne((v2-mean)*inv*w[lane+128]+bvec[lane+128]);
}

extern "C" void kernel_launch(void* const* d_in, const int* in_sizes, int n_in,
                              void* d_out, int out_size, void* d_ws, size_t ws_size,
                              hipStream_t stream){
  const float* x     =(const float*)d_in[0];
  const float* n1w   =(const float*)d_in[3];
  const float* n1b   =(const float*)d_in[4];
  const float* m_in_w=(const float*)d_in[5];
  const float* m_cw  =(const float*)d_in[6];
  const float* m_cb  =(const float*)d_in[7];
  const float* m_dtb =(const float*)d_in[8];
  const float* m_Al  =(const float*)d_in[9];
  const float* m_D   =(const float*)d_in[10];
  const float* m_nw  =(const float*)d_in[11];
  const float* m_ow  =(const float*)d_in[12];
  const float* qkvw  =(const float*)d_in[13];
  const float* qkvb  =(const float*)d_in[14];
  const float* projw =(const float*)d_in[15];
  const float* projb =(const float*)d_in[16];
  const float* gatew =(const float*)d_in[17];
  const float* gateb =(const float*)d_in[18];
  const float* fusw  =(const float*)d_in[19];
  const float* fusb  =(const float*)d_in[20];
  const float* ecaw  =(const float*)d_in[21];
  const float* n2w   =(const float*)d_in[22];
  const float* n2b   =(const float*)d_in[23];
  const float* fc1w  =(const float*)d_in[24];
  const float* fc1b  =(const float*)d_in[25];
  const float* fc2w  =(const float*)d_in[26];
  const float* fc2b  =(const float*)d_in[27];
  float* out=(float*)d_out;
  float* ws=(float*)d_ws;

  // arena (float offsets); bf16 buffers as short* aliases; zx stride = 904
  short* xn_bf  = (short*)(ws + 0);        //   884,736 fl [LN1 .. att2]
  short* wb     = (short*)(ws + 884736);   //   381,504 fl persistent
  short* zx_bf  = (short*)(ws + 1266240);  // 4,165,632 fl (9216x904) [in_proj .. rmsgate]
  short* xbc_bf = (short*)(ws + 5431872);  // 2,359,296 fl [conv .. ssd_b]
  float* dtb    = ws + 7791168;            //    55,296
  float* acs    = ws + 7846464;            //    55,296
  float* csum   = ws + 7901760;            //       512
  short* st_bf  = (short*)(ws + 7902272);  // 1,769,472 fl [ssd_a .. scan]
  short* prevb_bf=(short*)(ws + 9671744);  // 1,769,472 fl [scan .. ssd_b]
  short* Y_bf   = (short*)(ws + 11441216); // region 3,538,944 fl [ssd_a .. rmsgate]
  float* bigbf  = ws + 14980160;           // 3,538,944   (yn | h1 bf16)
  short* qkv_bf = (short*)(ws + 18519104); // 2,654,208 fl [inqkv .. att2]
  // aliases (disjoint lifetimes)
  short* hbuf_bf= xn_bf;                   // [xoln .. fc1]
  short* obuf_bf= xbc_bf;                  // [att2 .. proj] (xbc dead after ssd_b)
  short* xcat_bf= prevb_bf;                // [out_proj .. fusion]
  float* xf     = (float*)st_bf;           // [fusion .. xoln]
  float* xo     = (float*)Y_bf;            // [xoln .. fc2]
  short* yn_bf  = (short*)bigbf;           // [rmsgate .. out_proj]
  short* h1_bf  = (short*)bigbf;           // [fc1 .. fc2]
  float* partial= dtb;                     // ECA sums [rmsgate .. xoln]
  // bf16 weight segments
  short* wb_in  = wb + 0;
  short* wb_qkv = wb + 173184;
  short* wb_out = wb + 283776;
  short* wb_proj= wb + 357504;
  short* wb_fus = wb + 394368;
  short* wb_fc1 = wb + 468096;
  short* wb_fc2 = wb + 615552;

  // 1. LN1 + weight convert
  k_lnw2b<<<7043,256,0,stream>>>(x,n1w,n1b,xn_bf, m_in_w,qkvw,m_ow,projw,fusw,fc1w,fc2w,wb);
  // 2. in_proj + qkv
  k_gemm_inqkv<<<dim3(144,24),256,0,stream>>>(xn_bf,wb_in,zx_bf,wb_qkv,qkvb,qkv_bf);
  // 3. conv + prep
  k_convprep<<<2736,256,0,stream>>>(zx_bf,m_cw,m_cb,xbc_bf, m_dtb,m_Al,dtb,acs,csum);
  // 4. SSD part A
  k_ssd_a<<<432,256,0,stream>>>(xbc_bf,dtb,acs,csum,st_bf,Y_bf);
  // 5. chunk scan
  k_scan<<<192,256,0,stream>>>(st_bf,csum,prevb_bf);
  // 6. SSD part B
  k_ssd_b<<<432,256,0,stream>>>(xbc_bf,prevb_bf,acs,m_D,Y_bf);
  // 7. gated RMS norm (+ zero partial)
  k_rmsgate<<<2304,256,0,stream>>>(Y_bf,zx_bf,m_nw,yn_bf,partial);
  // 8. mamba out_proj -> xcat[:,0:192]
  k_gemm<384><<<dim3(144,3),256,0,stream>>>(yn_bf,wb_out,nullptr,nullptr,nullptr,xcat_bf, 192,384,0, 0,1,0, nullptr);
  // 9. attention (xbc dead -> obuf aliases it)
  k_att2<<<864,128,0,stream>>>(qkv_bf,xn_bf,gatew,gateb,obuf_bf);
  // 10. attn proj -> xcat[:,192:384]
  k_gemm<192><<<dim3(144,3),256,0,stream>>>(obuf_bf,wb_proj,projb,nullptr,nullptr,xcat_bf, 192,384,192, 0,2,0, nullptr);
  // 11. fusion -> xf fp32 + ECA pooling
  k_gemm<384><<<dim3(144,3),256,0,stream>>>(xcat_bf,wb_fus,fusb,nullptr,xf,nullptr, 192,192,0, 0,0,0, partial);
  // 12. fused xo + ECA sigmoid + LN2
  k_xoln<<<2304,256,0,stream>>>(x,xf,partial,ecaw,n2w,n2b,xo,hbuf_bf);
  // 13. fc1 + gelu
  k_gemm<192><<<dim3(144,12),256,0,stream>>>(hbuf_bf,wb_fc1,fc1b,nullptr,nullptr,h1_bf, 768,768,0, 0,0,2, nullptr);
  // 14. fc2 + residual -> out
  k_gemm<768><<<dim3(144,3),256,0,stream>>>(h1_bf,wb_fc2,fc2b,xo,out,nullptr, 192,192,0, 0,0,3, nullptr);
}